// Round 13
// baseline (404.895 us; speedup 1.0000x reference)
//
#include <hip/hip_runtime.h>

#define TT 4096
#define DD 1024
#define NN 32768   // B*T rows

typedef short s16x8 __attribute__((ext_vector_type(8)));
typedef float f32x4 __attribute__((ext_vector_type(4)));
typedef unsigned short ushort_t;

__device__ __forceinline__ unsigned short f2bf(float f) {
  unsigned u = __float_as_uint(f);
  u += 0x7FFFu + ((u >> 16) & 1u);
  return (unsigned short)(u >> 16);
}
__device__ __forceinline__ float bf2f(unsigned short h) {
  return __uint_as_float(((unsigned)h) << 16);
}
__device__ __forceinline__ void load_lds16(const void* g, void* l) {
  __builtin_amdgcn_global_load_lds(
      (const __attribute__((address_space(1))) unsigned int*)g,
      (__attribute__((address_space(3))) unsigned int*)l, 16, 0, 0);
}

// ---------------- weight conversion ----------------
__global__ __launch_bounds__(256)
void cvt_kernel(const float* __restrict__ s, ushort_t* __restrict__ d, int n) {
  int i = (blockIdx.x * 256 + threadIdx.x) * 4;
  if (i < n) {
    float4 v = *(const float4*)&s[i];
    ushort4 o; o.x = f2bf(v.x); o.y = f2bf(v.y); o.z = f2bf(v.z); o.w = f2bf(v.w);
    *(ushort4*)&d[i] = o;
  }
}

// concat dt_w/b_w/c_w into padded 256x1024 bf16 (rows 192..255 = 0)
__global__ __launch_bounds__(256)
void w3pad_kernel(const float* __restrict__ dt_w, const float* __restrict__ b_w,
                  const float* __restrict__ c_w, ushort_t* __restrict__ w3) {
  int e = (blockIdx.x * 256 + threadIdx.x) * 4;
  int row = e >> 10, col = e & 1023;
  float4 v; v.x = 0.f; v.y = 0.f; v.z = 0.f; v.w = 0.f;
  if (row < 64)       v = *(const float4*)&dt_w[(row << 10) + col];
  else if (row < 128) v = *(const float4*)&b_w[((row - 64) << 10) + col];
  else if (row < 192) v = *(const float4*)&c_w[((row - 128) << 10) + col];
  ushort4 o; o.x = f2bf(v.x); o.y = f2bf(v.y); o.z = f2bf(v.z); o.w = f2bf(v.w);
  *(ushort4*)&w3[e] = o;
}

// transpose 1024x1024 f32 -> bf16 (dst[k][j] = src[j][k])
__global__ __launch_bounds__(256)
void tpose_kernel(const float* __restrict__ src, ushort_t* __restrict__ dst) {
  __shared__ float tile[64][65];
  int bx = blockIdx.x & 15, by = blockIdx.x >> 4;
  int tx = threadIdx.x & 63, ty0 = threadIdx.x >> 6;
  #pragma unroll
  for (int i = 0; i < 16; ++i) {
    int ty = ty0 * 16 + i;
    tile[ty][tx] = src[(size_t)(by * 64 + ty) * 1024 + bx * 64 + tx];
  }
  __syncthreads();
  #pragma unroll
  for (int i = 0; i < 16; ++i) {
    int ty = ty0 * 16 + i;
    dst[(size_t)(bx * 64 + ty) * 1024 + by * 64 + tx] = f2bf(tile[tx][ty]);
  }
}

// composite gate bias: gb[i] = gate_bias[i] + sum_j W3[i,j]*in_b[1024+j]
__global__ void gbias_kernel(const float* __restrict__ dt_w, const float* __restrict__ b_w,
                             const float* __restrict__ c_w, const float* __restrict__ dt_b,
                             const float* __restrict__ b_b, const float* __restrict__ c_b,
                             const float* __restrict__ in_b, float* __restrict__ gb) {
  int i = blockIdx.x, lane = threadIdx.x;
  const float* wr = i < 64 ? dt_w + (size_t)i * 1024
                  : i < 128 ? b_w + (size_t)(i - 64) * 1024
                            : c_w + (size_t)(i - 128) * 1024;
  float s = 0.f;
  for (int j = lane; j < 1024; j += 64) s += wr[j] * in_b[1024 + j];
  #pragma unroll
  for (int off = 32; off; off >>= 1) s += __shfl_xor(s, off, 64);
  if (lane == 0) {
    float bb = i < 64 ? dt_b[i] : i < 128 ? b_b[i - 64] : c_b[i - 128];
    gb[i] = s + bb;
  }
}

// ---------------- LayerNorm -> bf16 ----------------
__global__ __launch_bounds__(256)
void ln_kernel(const float* __restrict__ x, const float* __restrict__ w,
               const float* __restrict__ bv, ushort_t* __restrict__ xn)
{
  int row = blockIdx.x * 4 + (threadIdx.x >> 6);
  int lane = threadIdx.x & 63;
  const float* xr = x + (size_t)row * DD;
  float4 v[4];
  float s = 0.f, ss = 0.f;
  #pragma unroll
  for (int j = 0; j < 4; ++j) {
    v[j] = *(const float4*)&xr[j * 256 + lane * 4];
    s  += v[j].x + v[j].y + v[j].z + v[j].w;
    ss += v[j].x * v[j].x + v[j].y * v[j].y + v[j].z * v[j].z + v[j].w * v[j].w;
  }
  #pragma unroll
  for (int off = 32; off > 0; off >>= 1) {
    s  += __shfl_xor(s, off, 64);
    ss += __shfl_xor(ss, off, 64);
  }
  float mean = s * (1.f / 1024.f);
  float var  = ss * (1.f / 1024.f) - mean * mean;
  float rinv = rsqrtf(var + 1e-5f);
  #pragma unroll
  for (int j = 0; j < 4; ++j) {
    int c = j * 256 + lane * 4;
    float4 wv = *(const float4*)&w[c];
    float4 bb = *(const float4*)&bv[c];
    ushort4 o;
    o.x = f2bf((v[j].x - mean) * rinv * wv.x + bb.x);
    o.y = f2bf((v[j].y - mean) * rinv * wv.y + bb.y);
    o.z = f2bf((v[j].z - mean) * rinv * wv.z + bb.z);
    o.w = f2bf((v[j].w - mean) * rinv * wv.w + bb.w);
    *(ushort4*)&xn[(size_t)row * DD + c] = o;
  }
}

// ---------------- 256x256 8-phase GEMM (round-4 verified schedule) ----------------
template<int EP>
__global__ __launch_bounds__(512, 2)
void gemm256(const ushort_t* __restrict__ A, const ushort_t* __restrict__ W,
             int M, int N, int K,
             const float* __restrict__ bias0,
             ushort_t* __restrict__ o0, ushort_t* __restrict__ o1)
{
  __shared__ ushort_t lds[65536];   // 128 KiB
  const int tid = threadIdx.x;
  const int lane = tid & 63;
  const int wid = tid >> 6;
  const int wr = wid >> 2;          // 0..1
  const int wc = wid & 3;           // 0..3
  const int lane15 = lane & 15;
  const int lgrp = lane >> 4;
  const int rsw = (lane15 & 7) << 4;
  const int ntn = N >> 8;
  int bid = blockIdx.x;
  { const int cpx = (int)gridDim.x >> 3; bid = (bid & 7) * cpx + (bid >> 3); }
  const int brow = (bid / ntn) << 8;
  const int bcol = (bid % ntn) << 8;
  const int nk = K >> 6;
  const int sRow = tid >> 3;        // 0..63
  const int sCol = (tid & 7) << 4;  // bytes 0..112
  const char* ldsb = (const char*)lds;
  (void)M;

#define STG(bufb, isB, h, kt) do { \
    const int ktc_ = (kt) < nk ? (kt) : nk - 1; \
    const ushort_t* gsrc_ = (isB) ? W : A; \
    const int rowb_ = ((isB) ? bcol : brow) + (h) * 128; \
    _Pragma("unroll") \
    for (int j_ = 0; j_ < 2; ++j_) { \
      const int r_ = j_ * 64 + sRow; \
      load_lds16((const char*)(gsrc_ + (size_t)(rowb_ + r_) * K) + ktc_ * 128 + (sCol ^ ((r_ & 7) << 4)), \
                 (char*)lds + (bufb) * 65536 + (isB) * 32768 + (h) * 16384 + r_ * 128 + sCol); \
    } } while (0)

#define LDA_(bufb, m, kk) \
  (*(const s16x8*)(ldsb + (bufb) * 65536 + wr * 16384 + ((m) * 16 + lane15) * 128 + (((kk) * 64 + lgrp * 16) ^ rsw)))
#define LDB_(bufb, n, kk) \
  (*(const s16x8*)(ldsb + (bufb) * 65536 + 32768 + (wc >> 1) * 16384 + ((wc & 1) * 64 + (n) * 16 + lane15) * 128 + (((kk) * 64 + lgrp * 16) ^ rsw)))

#define BARR() asm volatile("s_barrier" ::: "memory")
#define VMW2() asm volatile("s_waitcnt vmcnt(2)" ::: "memory")
#define VMW4() asm volatile("s_waitcnt vmcnt(4)" ::: "memory")

#define RDA(dst, bufb, mh) do { \
    _Pragma("unroll") for (int kk = 0; kk < 2; ++kk) \
    _Pragma("unroll") for (int q = 0; q < 4; ++q) \
      dst[kk][q] = LDA_(bufb, (mh) * 4 + q, kk); } while (0)
#define RDB(dst, bufb, nh) do { \
    _Pragma("unroll") for (int kk = 0; kk < 2; ++kk) \
    _Pragma("unroll") for (int p = 0; p < 2; ++p) \
      dst[kk][p] = LDB_(bufb, (nh) * 2 + p, kk); } while (0)

#define MFMAQ(AF, BF, mh, nh) do { \
    __builtin_amdgcn_s_setprio(1); \
    _Pragma("unroll") for (int kk = 0; kk < 2; ++kk) \
    _Pragma("unroll") for (int q = 0; q < 4; ++q) \
    _Pragma("unroll") for (int p = 0; p < 2; ++p) \
      acc[(mh) * 4 + q][(nh) * 2 + p] = __builtin_amdgcn_mfma_f32_16x16x32_bf16( \
          AF[kk][q], BF[kk][p], acc[(mh) * 4 + q][(nh) * 2 + p], 0, 0, 0); \
    __builtin_amdgcn_s_setprio(0); } while (0)

  f32x4 acc[8][4];
  #pragma unroll
  for (int m = 0; m < 8; ++m) {
    #pragma unroll
    for (int n = 0; n < 4; ++n) acc[m][n] = (f32x4){0.f, 0.f, 0.f, 0.f};
  }
  s16x8 afP[2][4], afQ[2][4];
  s16x8 b0[2][2], b1[2][2];

  STG(0, 1, 0, 0); STG(0, 0, 0, 0); STG(0, 0, 1, 0); STG(0, 1, 1, 0);
  STG(1, 1, 0, 1); STG(1, 0, 0, 1);
  VMW4(); BARR();
  RDA(afP, 0, 0); RDB(b0, 0, 0);

  const int nIter = nk >> 1;
  for (int it = 0; it < nIter; ++it) {
    const int t0 = 2 * it;
    STG(1, 0, 1, t0 + 1);
    MFMAQ(afP, b0, 0, 0);
    RDB(b1, 0, 1); BARR();
    STG(1, 1, 1, t0 + 1);
    MFMAQ(afP, b1, 0, 1);
    RDA(afQ, 0, 1); BARR();
    STG(0, 1, 0, t0 + 2);
    MFMAQ(afQ, b1, 1, 1);
    VMW2(); BARR();
    STG(0, 0, 0, t0 + 2);
    MFMAQ(afQ, b0, 1, 0);
    RDA(afP, 1, 0); RDB(b1, 1, 1); BARR();
    STG(0, 0, 1, t0 + 2);
    MFMAQ(afP, b1, 0, 1);
    RDB(b0, 1, 0); BARR();
    STG(0, 1, 1, t0 + 2);
    MFMAQ(afP, b0, 0, 0);
    RDA(afQ, 1, 1); BARR();
    STG(1, 1, 0, t0 + 3);
    MFMAQ(afQ, b0, 1, 0);
    VMW2(); BARR();
    STG(1, 0, 0, t0 + 3);
    MFMAQ(afQ, b1, 1, 1);
    RDA(afP, 0, 0); RDB(b0, 0, 0); BARR();
  }
  if (nk & 1) {
    MFMAQ(afP, b0, 0, 0);
    RDB(b1, 0, 1);
    MFMAQ(afP, b1, 0, 1);
    RDA(afQ, 0, 1);
    MFMAQ(afQ, b1, 1, 1);
    MFMAQ(afQ, b0, 1, 0);
  }

#undef STG
#undef LDA_
#undef LDB_
#undef BARR
#undef VMW2
#undef VMW4
#undef RDA
#undef RDB
#undef MFMAQ

  #pragma unroll
  for (int m = 0; m < 8; ++m) {
    #pragma unroll
    for (int i = 0; i < 4; ++i) {
      const int r = brow + wr * 128 + m * 16 + lgrp * 4 + i;
      #pragma unroll
      for (int n = 0; n < 4; ++n) {
        const int col = bcol + wc * 64 + n * 16 + lane15;
        float v = acc[m][n][i] + bias0[col];
        if (col < DD) o0[(size_t)r * DD + col] = f2bf(v);
        else          o1[(size_t)r * DD + (col - DD)] = f2bf(v);
      }
    }
  }
}

// ---------------- GEMM3: 64x128 tile, BK=64, 3 blocks/CU, resid prefetch ------
// 4 waves, each 64(M) x 32(N) out (acc 32 VGPR); LDS 48 KiB (2 bufs x 24 KiB).
// Staging uses the canonical lane-order pattern (lds_off(lane) = base + lane*16):
// sR = tid>>3 (32-row slabs), sC = (tid&7)<<4; swizzled source + swizzled read.
__global__ __launch_bounds__(256, 3)
void gemm3_64(const ushort_t* __restrict__ A, const ushort_t* __restrict__ W,
              int M, int N, int K,
              const float* __restrict__ bias, const float* __restrict__ resid,
              float* __restrict__ outf)
{
  __shared__ ushort_t lds[24576];   // 48 KiB: per buf 24KB = A[64][64] + B[128][64]
  const int tid = threadIdx.x;
  const int lane = tid & 63;
  const int wc = tid >> 6;          // 0..3 (wave = 32-col quarter)
  const int lane15 = lane & 15;
  const int lgrp = lane >> 4;
  const int rsw = (lane15 & 7) << 4;
  const int ntn = N >> 7;           // 8
  int bid = blockIdx.x;
  { const int cpx = (int)gridDim.x >> 3; bid = (bid & 7) * cpx + (bid >> 3); }
  const int brow = (bid / ntn) << 6;    // 64-row tile
  const int bcol = (bid % ntn) << 7;    // 128-col tile
  const int nk = K >> 6;                // 17
  const int sR = tid >> 3;              // 0..31
  const int sC = (tid & 7) << 4;        // bytes 0..112
  const char* ldsb = (const char*)lds;
  (void)M;

  f32x4 acc[4][2];
  #pragma unroll
  for (int q = 0; q < 4; ++q)
    #pragma unroll
    for (int p = 0; p < 2; ++p) acc[q][p] = (f32x4){0.f, 0.f, 0.f, 0.f};
  float rs[32];

#define STG3(bufb, kt) do { \
    _Pragma("unroll") \
    for (int j_ = 0; j_ < 2; ++j_) { \
      const int r_ = j_ * 32 + sR; \
      load_lds16((const char*)(A + (size_t)(brow + r_) * K) + (kt) * 128 + (sC ^ ((r_ & 7) << 4)), \
                 (char*)lds + (bufb) * 24576 + r_ * 128 + sC); \
    } \
    _Pragma("unroll") \
    for (int j_ = 0; j_ < 4; ++j_) { \
      const int r_ = j_ * 32 + sR; \
      load_lds16((const char*)(W + (size_t)(bcol + r_) * K) + (kt) * 128 + (sC ^ ((r_ & 7) << 4)), \
                 (char*)lds + (bufb) * 24576 + 8192 + r_ * 128 + sC); \
    } } while (0)

  STG3(0, 0);
  __syncthreads();

  int cur = 0;
  for (int t = 0; t < nk; ++t) {
    if (t + 1 < nk) STG3(cur ^ 1, t + 1);
    if (t == nk - 4) {      // prefetch resid 4 tiles early (lands before epilogue)
      #pragma unroll
      for (int q = 0; q < 4; ++q)
        #pragma unroll
        for (int p = 0; p < 2; ++p)
          #pragma unroll
          for (int i = 0; i < 4; ++i)
            rs[q * 8 + p * 4 + i] =
              resid[(size_t)(brow + q * 16 + lgrp * 4 + i) * DD + bcol + wc * 32 + p * 16 + lane15];
    }
    #pragma unroll
    for (int kk = 0; kk < 2; ++kk) {
      s16x8 af[4], bf[2];
      #pragma unroll
      for (int q = 0; q < 4; ++q)
        af[q] = *(const s16x8*)(ldsb + cur * 24576 +
                 (q * 16 + lane15) * 128 + ((kk * 64 + lgrp * 16) ^ rsw));
      #pragma unroll
      for (int p = 0; p < 2; ++p)
        bf[p] = *(const s16x8*)(ldsb + cur * 24576 + 8192 +
                 (wc * 32 + p * 16 + lane15) * 128 + ((kk * 64 + lgrp * 16) ^ rsw));
      __builtin_amdgcn_s_setprio(1);
      #pragma unroll
      for (int q = 0; q < 4; ++q)
        #pragma unroll
        for (int p = 0; p < 2; ++p)
          acc[q][p] = __builtin_amdgcn_mfma_f32_16x16x32_bf16(af[q], bf[p], acc[q][p], 0, 0, 0);
      __builtin_amdgcn_s_setprio(0);
    }
    __syncthreads();
    cur ^= 1;
  }
#undef STG3

  #pragma unroll
  for (int q = 0; q < 4; ++q) {
    #pragma unroll
    for (int i = 0; i < 4; ++i) {
      const int r = brow + q * 16 + lgrp * 4 + i;
      #pragma unroll
      for (int p = 0; p < 2; ++p) {
        const int col = bcol + wc * 32 + p * 16 + lane15;
        outf[(size_t)r * DD + col] = acc[q][p][i] + bias[col] + rs[q * 8 + p * 4 + i];
      }
    }
  }
}

// ---------------- 128x128 2-phase GEMM, bf16 out (weight-prep fold) ----------------
__global__ __launch_bounds__(256)
void gemm128w(const ushort_t* __restrict__ A, const ushort_t* __restrict__ W,
              int M, int N, int K, ushort_t* __restrict__ o0)
{
  __shared__ ushort_t As[128 * 64];
  __shared__ ushort_t Bs[128 * 64];
  const int tid = threadIdx.x;
  const int lane = tid & 63;
  const int wid = tid >> 6;
  const int ntn = N >> 7;
  const int brow = (blockIdx.x / ntn) << 7;
  const int bcol = (blockIdx.x % ntn) << 7;
  const int wr = (wid >> 1) << 6;
  const int wc = (wid & 1) << 6;
  const int lane15 = lane & 15;
  const int lgrp = lane >> 4;
  (void)M;

  f32x4 acc[4][4];
  #pragma unroll
  for (int m = 0; m < 4; ++m)
    #pragma unroll
    for (int n = 0; n < 4; ++n)
      acc[m][n] = (f32x4){0.f, 0.f, 0.f, 0.f};

  const int r0 = tid >> 3;
  const int c0 = (tid & 7) << 3;
  const ushort_t* gA = A + (size_t)(brow + r0) * K + c0;
  const ushort_t* gW = W + (size_t)(bcol + r0) * K + c0;
  ushort_t* lA = &As[r0 * 64 + c0];
  ushort_t* lB = &Bs[r0 * 64 + c0];

  for (int k0 = 0; k0 < K; k0 += 64) {
    #pragma unroll
    for (int j = 0; j < 4; ++j) {
      load_lds16(gA + (size_t)(j * 32) * K + k0, lA + j * 32 * 64);
      load_lds16(gW + (size_t)(j * 32) * K + k0, lB + j * 32 * 64);
    }
    __syncthreads();
    #pragma unroll
    for (int kk = 0; kk < 2; ++kk) {
      s16x8 af[4], bfr[4];
      #pragma unroll
      for (int m = 0; m < 4; ++m)
        af[m] = *(const s16x8*)&As[(wr + m * 16 + lane15) * 64 + kk * 32 + lgrp * 8];
      #pragma unroll
      for (int n = 0; n < 4; ++n)
        bfr[n] = *(const s16x8*)&Bs[(wc + n * 16 + lane15) * 64 + kk * 32 + lgrp * 8];
      #pragma unroll
      for (int m = 0; m < 4; ++m)
        #pragma unroll
        for (int n = 0; n < 4; ++n)
          acc[m][n] = __builtin_amdgcn_mfma_f32_16x16x32_bf16(af[m], bfr[n], acc[m][n], 0, 0, 0);
    }
    __syncthreads();
  }

  #pragma unroll
  for (int m = 0; m < 4; ++m) {
    #pragma unroll
    for (int i = 0; i < 4; ++i) {
      const int r = brow + wr + m * 16 + lgrp * 4 + i;
      #pragma unroll
      for (int n = 0; n < 4; ++n) {
        const int col = bcol + wc + n * 16 + lane15;
        o0[(size_t)r * N + col] = f2bf(acc[m][n][i]);
      }
    }
  }
}

// ---------------- 128x128 2-phase GEMM: gates from xn (composite W/bias) --------
__global__ __launch_bounds__(256)
void gemm128g(const ushort_t* __restrict__ A, const ushort_t* __restrict__ W,
              int M, int N, int K,
              const float* __restrict__ gb, const float* __restrict__ alog,
              float* __restrict__ g0, float* __restrict__ g1, float* __restrict__ g2)
{
  __shared__ ushort_t As[128 * 64];
  __shared__ ushort_t Bs[128 * 64];
  const int tid = threadIdx.x;
  const int lane = tid & 63;
  const int wid = tid >> 6;
  const int ntn = N >> 7;
  const int brow = (blockIdx.x / ntn) << 7;
  const int bcol = (blockIdx.x % ntn) << 7;
  const int wr = (wid >> 1) << 6;
  const int wc = (wid & 1) << 6;
  const int lane15 = lane & 15;
  const int lgrp = lane >> 4;
  (void)M;

  f32x4 acc[4][4];
  #pragma unroll
  for (int m = 0; m < 4; ++m)
    #pragma unroll
    for (int n = 0; n < 4; ++n)
      acc[m][n] = (f32x4){0.f, 0.f, 0.f, 0.f};

  const int r0 = tid >> 3;
  const int c0 = (tid & 7) << 3;
  const ushort_t* gA = A + (size_t)(brow + r0) * K + c0;
  const ushort_t* gW = W + (size_t)(bcol + r0) * K + c0;
  ushort_t* lA = &As[r0 * 64 + c0];
  ushort_t* lB = &Bs[r0 * 64 + c0];

  for (int k0 = 0; k0 < K; k0 += 64) {
    #pragma unroll
    for (int j = 0; j < 4; ++j) {
      load_lds16(gA + (size_t)(j * 32) * K + k0, lA + j * 32 * 64);
      load_lds16(gW + (size_t)(j * 32) * K + k0, lB + j * 32 * 64);
    }
    __syncthreads();
    #pragma unroll
    for (int kk = 0; kk < 2; ++kk) {
      s16x8 af[4], bfr[4];
      #pragma unroll
      for (int m = 0; m < 4; ++m)
        af[m] = *(const s16x8*)&As[(wr + m * 16 + lane15) * 64 + kk * 32 + lgrp * 8];
      #pragma unroll
      for (int n = 0; n < 4; ++n)
        bfr[n] = *(const s16x8*)&Bs[(wc + n * 16 + lane15) * 64 + kk * 32 + lgrp * 8];
      #pragma unroll
      for (int m = 0; m < 4; ++m)
        #pragma unroll
        for (int n = 0; n < 4; ++n)
          acc[m][n] = __builtin_amdgcn_mfma_f32_16x16x32_bf16(af[m], bfr[n], acc[m][n], 0, 0, 0);
    }
    __syncthreads();
  }

  #pragma unroll
  for (int m = 0; m < 4; ++m) {
    #pragma unroll
    for (int i = 0; i < 4; ++i) {
      const int r = brow + wr + m * 16 + lgrp * 4 + i;
      #pragma unroll
      for (int n = 0; n < 4; ++n) {
        const int col = bcol + wc + n * 16 + lane15;
        float v = acc[m][n][i];
        if (col < 64) {
          float u = v + gb[col];
          float sp = (u > 20.f) ? u : log1pf(expf(u));
          g0[(size_t)r * 64 + col] = expf(-expf(alog[col]) * (sp + 1e-4f));
        } else if (col < 128) {
          g1[(size_t)r * 64 + (col - 64)] = tanhf(v + gb[col]);
        } else if (col < 192) {
          g2[(size_t)r * 64 + (col - 128)] = tanhf(v + gb[col]);
        }
      }
    }
  }
}

// ---------------- depthwise conv K=3 + tanh + *d -> mix[:, :D] ----------------
__global__ __launch_bounds__(256)
void conv_kernel(const ushort_t* __restrict__ xp, const float* __restrict__ cw,
                 const float* __restrict__ cb, const float* __restrict__ dvec,
                 ushort_t* __restrict__ mix)
{
  int idx = blockIdx.x * 256 + threadIdx.x;
  int row = idx >> 7;
  int d0 = (idx & 127) << 3;
  int t = row & (TT - 1);
  s16x8 cur = *(const s16x8*)&xp[(size_t)row * DD + d0];
  s16x8 prv; s16x8 nxt;
  #pragma unroll
  for (int j = 0; j < 8; ++j) { prv[j] = 0; nxt[j] = 0; }
  if (t > 0)      prv = *(const s16x8*)&xp[(size_t)(row - 1) * DD + d0];
  if (t < TT - 1) nxt = *(const s16x8*)&xp[(size_t)(row + 1) * DD + d0];
  float wv[24];
  #pragma unroll
  for (int j = 0; j < 6; ++j) *(float4*)&wv[j * 4] = *(const float4*)&cw[d0 * 3 + j * 4];
  float cbv[8], dv[8];
  *(float4*)&cbv[0] = *(const float4*)&cb[d0];
  *(float4*)&cbv[4] = *(const float4*)&cb[d0 + 4];
  *(float4*)&dv[0]  = *(const float4*)&dvec[d0];
  *(float4*)&dv[4]  = *(const float4*)&dvec[d0 + 4];
  s16x8 o;
  #pragma unroll
  for (int j = 0; j < 8; ++j) {
    float acc = cbv[j] + bf2f((ushort_t)prv[j]) * wv[j * 3]
              + bf2f((ushort_t)cur[j]) * wv[j * 3 + 1]
              + bf2f((ushort_t)nxt[j]) * wv[j * 3 + 2];
    o[j] = (short)f2bf(tanhf(acc) * dv[j]);
  }
  *(s16x8*)&mix[(size_t)row * 1088 + d0] = o;
}

// ---------------- chunked scan ----------------
__global__ void scanA_kernel(const float* __restrict__ dec, const float* __restrict__ bb,
                             float* __restrict__ P, float* __restrict__ Q)
{
  int b = blockIdx.x >> 6, ci = blockIdx.x & 63, s = threadIdx.x;
  size_t base = (((size_t)b * TT) + ci * 64) * 64 + s;
  float p = 1.f, q = 0.f;
  #pragma unroll 4
  for (int t = 0; t < 64; ++t) {
    float d = dec[base + (size_t)t * 64];
    float w = bb[base + (size_t)t * 64];
    q = q * d + w; p *= d;
  }
  int o = (b * 64 + ci) * 64 + s;
  P[o] = p; Q[o] = q;
}

__global__ void scanB_kernel(const float* __restrict__ P, const float* __restrict__ Q,
                             float* __restrict__ I)
{
  int b = blockIdx.x, s = threadIdx.x;
  float pv[64], qv[64];
  #pragma unroll
  for (int ci = 0; ci < 64; ++ci) {
    int o = (b * 64 + ci) * 64 + s;
    pv[ci] = P[o]; qv[ci] = Q[o];
  }
  float st = 0.f;
  #pragma unroll
  for (int ci = 0; ci < 64; ++ci) {
    int o = (b * 64 + ci) * 64 + s;
    I[o] = st;
    st = st * pv[ci] + qv[ci];
  }
}

__global__ void scanC_kernel(const float* __restrict__ dec, const float* __restrict__ bb,
                             const float* __restrict__ cc, const float* __restrict__ I,
                             ushort_t* __restrict__ mix)
{
  int b = blockIdx.x >> 6, ci = blockIdx.x & 63, s = threadIdx.x;
  size_t base = (((size_t)b * TT) + ci * 64) * 64 + s;
  float st = I[(b * 64 + ci) * 64 + s];
  size_t mrow = (size_t)b * TT + ci * 64;
  #pragma unroll 4
  for (int t = 0; t < 64; ++t) {
    size_t o = base + (size_t)t * 64;
    st = st * dec[o] + bb[o];
    mix[(mrow + t) * 1088 + 1024 + s] = (ushort_t)f2bf(cc[o] * st);
  }
}

// ---------------- launch ----------------
extern "C" void kernel_launch(void* const* d_in, const int* in_sizes, int n_in,
                              void* d_out, int out_size, void* d_ws, size_t ws_size,
                              hipStream_t stream)
{
  (void)in_sizes; (void)n_in; (void)out_size; (void)ws_size;
  const float* x      = (const float*)d_in[0];
  const float* norm_w = (const float*)d_in[1];
  const float* norm_b = (const float*)d_in[2];
  const float* in_w   = (const float*)d_in[3];
  const float* in_b   = (const float*)d_in[4];
  const float* conv_w = (const float*)d_in[5];
  const float* conv_b = (const float*)d_in[6];
  const float* dt_w   = (const float*)d_in[7];
  const float* dt_b   = (const float*)d_in[8];
  const float* b_w    = (const float*)d_in[9];
  const float* b_b    = (const float*)d_in[10];
  const float* c_w    = (const float*)d_in[11];
  const float* c_b    = (const float*)d_in[12];
  const float* a_log  = (const float*)d_in[13];
  const float* dvec   = (const float*)d_in[14];
  const float* out_w  = (const float*)d_in[15];
  const float* out_b  = (const float*)d_in[16];
  float* out = (float*)d_out;

  char* p = (char*)d_ws;
  ushort_t* mix    = (ushort_t*)p;               // NN x 1088 bf16 (xn aliases head)
  ushort_t* xn     = mix;
  p += 71303168;
  ushort_t* xproj  = (ushort_t*)p; p += 67108864;
  char*     zreg   = p;            p += 67108864; // gates + fold scratch
  ushort_t* w1_bf  = (ushort_t*)p; p += 4194304;  // 1024x1024 bf16 (xproj weight)
  ushort_t* w3     = (ushort_t*)p; p += 524288;   // 256x1024 bf16 (orig gate W, padded)
  ushort_t* outw_bf= (ushort_t*)p; p += 2228224;
  float* P = (float*)p; p += 131072;
  float* Q = (float*)p; p += 131072;
  float* I = (float*)p; p += 131072;

  float* gdec = (float*)zreg;                        // NN x 64 f32
  float* gbb  = (float*)(zreg + 8388608);
  float* gcc  = (float*)(zreg + 16777216);
  ushort_t* inw2t  = (ushort_t*)(zreg + 33554432);   // 1024x1024 bf16 (dead after fold)
  float*    gb     = (float*)(zreg + 37748736);      // 192 f32 composite bias
  ushort_t* wgates = (ushort_t*)(zreg + 41943040);   // 256x1024 bf16 composite gate W

  // --- weight prep ---
  cvt_kernel<<<1024, 256, 0, stream>>>(in_w, w1_bf, 1048576);        // W1 (rows 0..1023)
  cvt_kernel<<<1088, 256, 0, stream>>>(out_w, outw_bf, 1114112);
  tpose_kernel<<<256, 256, 0, stream>>>(in_w + 1048576, inw2t);      // in_w2^T
  w3pad_kernel<<<256, 256, 0, stream>>>(dt_w, b_w, c_w, w3);
  gemm128w<<<16, 256, 0, stream>>>(w3, inw2t, 256, 1024, 1024, wgates);  // Wg = W3 @ W2
  gbias_kernel<<<192, 64, 0, stream>>>(dt_w, b_w, c_w, dt_b, b_b, c_b, in_b, gb);

  ln_kernel<<<8192, 256, 0, stream>>>(x, norm_w, norm_b, xn);

  // GEMM1a: xproj = xn @ W1^T + in_b[:1024]   (M=32768, N=1024, K=1024)
  gemm256<0><<<(NN / 256) * (1024 / 256), 512, 0, stream>>>(
      xn, w1_bf, NN, 1024, 1024, in_b, xproj, nullptr);

  // GEMM2': gates = xn @ Wg^T + gb  (runs BEFORE conv overwrites mix/xn)
  gemm128g<<<(NN / 128) * (256 / 128), 256, 0, stream>>>(
      xn, wgates, NN, 256, 1024, gb, a_log, gdec, gbb, gcc);

  conv_kernel<<<NN * 128 / 256, 256, 0, stream>>>(xproj, conv_w, conv_b, dvec, mix);

  scanA_kernel<<<512, 64, 0, stream>>>(gdec, gbb, P, Q);
  scanB_kernel<<<8, 64, 0, stream>>>(P, Q, I);
  scanC_kernel<<<512, 64, 0, stream>>>(gdec, gbb, gcc, I, mix);

  // GEMM3: out = mix @ out_w^T + out_b + x  (K=1088, nk=17; 3 blocks/CU, resid prefetch)
  gemm3_64<<<(NN / 64) * (1024 / 128), 256, 0, stream>>>(
      mix, outw_bf, NN, 1024, 1088, out_b, x, out);
}

// Round 14
// 393.224 us; speedup vs baseline: 1.0297x; 1.0297x over previous
//
#include <hip/hip_runtime.h>

#define TT 4096
#define DD 1024
#define NN 32768   // B*T rows

typedef short s16x8 __attribute__((ext_vector_type(8)));
typedef float f32x4 __attribute__((ext_vector_type(4)));
typedef unsigned short ushort_t;

__device__ __forceinline__ unsigned short f2bf(float f) {
  unsigned u = __float_as_uint(f);
  u += 0x7FFFu + ((u >> 16) & 1u);
  return (unsigned short)(u >> 16);
}
__device__ __forceinline__ float bf2f(unsigned short h) {
  return __uint_as_float(((unsigned)h) << 16);
}
__device__ __forceinline__ void load_lds16(const void* g, void* l) {
  __builtin_amdgcn_global_load_lds(
      (const __attribute__((address_space(1))) unsigned int*)g,
      (__attribute__((address_space(3))) unsigned int*)l, 16, 0, 0);
}

// ---------------- weight conversion ----------------
__global__ __launch_bounds__(256)
void cvt_kernel(const float* __restrict__ s, ushort_t* __restrict__ d, int n) {
  int i = (blockIdx.x * 256 + threadIdx.x) * 4;
  if (i < n) {
    float4 v = *(const float4*)&s[i];
    ushort4 o; o.x = f2bf(v.x); o.y = f2bf(v.y); o.z = f2bf(v.z); o.w = f2bf(v.w);
    *(ushort4*)&d[i] = o;
  }
}

// concat dt_w/b_w/c_w into padded 256x1024 bf16 (rows 192..255 = 0)
__global__ __launch_bounds__(256)
void w3pad_kernel(const float* __restrict__ dt_w, const float* __restrict__ b_w,
                  const float* __restrict__ c_w, ushort_t* __restrict__ w3) {
  int e = (blockIdx.x * 256 + threadIdx.x) * 4;
  int row = e >> 10, col = e & 1023;
  float4 v; v.x = 0.f; v.y = 0.f; v.z = 0.f; v.w = 0.f;
  if (row < 64)       v = *(const float4*)&dt_w[(row << 10) + col];
  else if (row < 128) v = *(const float4*)&b_w[((row - 64) << 10) + col];
  else if (row < 192) v = *(const float4*)&c_w[((row - 128) << 10) + col];
  ushort4 o; o.x = f2bf(v.x); o.y = f2bf(v.y); o.z = f2bf(v.z); o.w = f2bf(v.w);
  *(ushort4*)&w3[e] = o;
}

// transpose 1024x1024 f32 -> bf16 (dst[k][j] = src[j][k])
__global__ __launch_bounds__(256)
void tpose_kernel(const float* __restrict__ src, ushort_t* __restrict__ dst) {
  __shared__ float tile[64][65];
  int bx = blockIdx.x & 15, by = blockIdx.x >> 4;
  int tx = threadIdx.x & 63, ty0 = threadIdx.x >> 6;
  #pragma unroll
  for (int i = 0; i < 16; ++i) {
    int ty = ty0 * 16 + i;
    tile[ty][tx] = src[(size_t)(by * 64 + ty) * 1024 + bx * 64 + tx];
  }
  __syncthreads();
  #pragma unroll
  for (int i = 0; i < 16; ++i) {
    int ty = ty0 * 16 + i;
    dst[(size_t)(bx * 64 + ty) * 1024 + by * 64 + tx] = f2bf(tile[tx][ty]);
  }
}

// composite gate bias: gb[i] = gate_bias[i] + sum_j W3[i,j]*in_b[1024+j]
__global__ void gbias_kernel(const float* __restrict__ dt_w, const float* __restrict__ b_w,
                             const float* __restrict__ c_w, const float* __restrict__ dt_b,
                             const float* __restrict__ b_b, const float* __restrict__ c_b,
                             const float* __restrict__ in_b, float* __restrict__ gb) {
  int i = blockIdx.x, lane = threadIdx.x;
  const float* wr = i < 64 ? dt_w + (size_t)i * 1024
                  : i < 128 ? b_w + (size_t)(i - 64) * 1024
                            : c_w + (size_t)(i - 128) * 1024;
  float s = 0.f;
  for (int j = lane; j < 1024; j += 64) s += wr[j] * in_b[1024 + j];
  #pragma unroll
  for (int off = 32; off; off >>= 1) s += __shfl_xor(s, off, 64);
  if (lane == 0) {
    float bb = i < 64 ? dt_b[i] : i < 128 ? b_b[i - 64] : c_b[i - 128];
    gb[i] = s + bb;
  }
}

// ---------------- LayerNorm -> bf16 ----------------
__global__ __launch_bounds__(256)
void ln_kernel(const float* __restrict__ x, const float* __restrict__ w,
               const float* __restrict__ bv, ushort_t* __restrict__ xn)
{
  int row = blockIdx.x * 4 + (threadIdx.x >> 6);
  int lane = threadIdx.x & 63;
  const float* xr = x + (size_t)row * DD;
  float4 v[4];
  float s = 0.f, ss = 0.f;
  #pragma unroll
  for (int j = 0; j < 4; ++j) {
    v[j] = *(const float4*)&xr[j * 256 + lane * 4];
    s  += v[j].x + v[j].y + v[j].z + v[j].w;
    ss += v[j].x * v[j].x + v[j].y * v[j].y + v[j].z * v[j].z + v[j].w * v[j].w;
  }
  #pragma unroll
  for (int off = 32; off > 0; off >>= 1) {
    s  += __shfl_xor(s, off, 64);
    ss += __shfl_xor(ss, off, 64);
  }
  float mean = s * (1.f / 1024.f);
  float var  = ss * (1.f / 1024.f) - mean * mean;
  float rinv = rsqrtf(var + 1e-5f);
  #pragma unroll
  for (int j = 0; j < 4; ++j) {
    int c = j * 256 + lane * 4;
    float4 wv = *(const float4*)&w[c];
    float4 bb = *(const float4*)&bv[c];
    ushort4 o;
    o.x = f2bf((v[j].x - mean) * rinv * wv.x + bb.x);
    o.y = f2bf((v[j].y - mean) * rinv * wv.y + bb.y);
    o.z = f2bf((v[j].z - mean) * rinv * wv.z + bb.z);
    o.w = f2bf((v[j].w - mean) * rinv * wv.w + bb.w);
    *(ushort4*)&xn[(size_t)row * DD + c] = o;
  }
}

// ---------------- 256x256 8-phase GEMM (round-4 verified schedule) ----------------
template<int EP>
__global__ __launch_bounds__(512, 2)
void gemm256(const ushort_t* __restrict__ A, const ushort_t* __restrict__ W,
             int M, int N, int K,
             const float* __restrict__ bias0,
             ushort_t* __restrict__ o0, ushort_t* __restrict__ o1)
{
  __shared__ ushort_t lds[65536];   // 128 KiB
  const int tid = threadIdx.x;
  const int lane = tid & 63;
  const int wid = tid >> 6;
  const int wr = wid >> 2;          // 0..1
  const int wc = wid & 3;           // 0..3
  const int lane15 = lane & 15;
  const int lgrp = lane >> 4;
  const int rsw = (lane15 & 7) << 4;
  const int ntn = N >> 8;
  int bid = blockIdx.x;
  { const int cpx = (int)gridDim.x >> 3; bid = (bid & 7) * cpx + (bid >> 3); }
  const int brow = (bid / ntn) << 8;
  const int bcol = (bid % ntn) << 8;
  const int nk = K >> 6;
  const int sRow = tid >> 3;        // 0..63
  const int sCol = (tid & 7) << 4;  // bytes 0..112
  const char* ldsb = (const char*)lds;
  (void)M;

#define STG(bufb, isB, h, kt) do { \
    const int ktc_ = (kt) < nk ? (kt) : nk - 1; \
    const ushort_t* gsrc_ = (isB) ? W : A; \
    const int rowb_ = ((isB) ? bcol : brow) + (h) * 128; \
    _Pragma("unroll") \
    for (int j_ = 0; j_ < 2; ++j_) { \
      const int r_ = j_ * 64 + sRow; \
      load_lds16((const char*)(gsrc_ + (size_t)(rowb_ + r_) * K) + ktc_ * 128 + (sCol ^ ((r_ & 7) << 4)), \
                 (char*)lds + (bufb) * 65536 + (isB) * 32768 + (h) * 16384 + r_ * 128 + sCol); \
    } } while (0)

#define LDA_(bufb, m, kk) \
  (*(const s16x8*)(ldsb + (bufb) * 65536 + wr * 16384 + ((m) * 16 + lane15) * 128 + (((kk) * 64 + lgrp * 16) ^ rsw)))
#define LDB_(bufb, n, kk) \
  (*(const s16x8*)(ldsb + (bufb) * 65536 + 32768 + (wc >> 1) * 16384 + ((wc & 1) * 64 + (n) * 16 + lane15) * 128 + (((kk) * 64 + lgrp * 16) ^ rsw)))

#define BARR() asm volatile("s_barrier" ::: "memory")
#define VMW2() asm volatile("s_waitcnt vmcnt(2)" ::: "memory")
#define VMW4() asm volatile("s_waitcnt vmcnt(4)" ::: "memory")

#define RDA(dst, bufb, mh) do { \
    _Pragma("unroll") for (int kk = 0; kk < 2; ++kk) \
    _Pragma("unroll") for (int q = 0; q < 4; ++q) \
      dst[kk][q] = LDA_(bufb, (mh) * 4 + q, kk); } while (0)
#define RDB(dst, bufb, nh) do { \
    _Pragma("unroll") for (int kk = 0; kk < 2; ++kk) \
    _Pragma("unroll") for (int p = 0; p < 2; ++p) \
      dst[kk][p] = LDB_(bufb, (nh) * 2 + p, kk); } while (0)

#define MFMAQ(AF, BF, mh, nh) do { \
    __builtin_amdgcn_s_setprio(1); \
    _Pragma("unroll") for (int kk = 0; kk < 2; ++kk) \
    _Pragma("unroll") for (int q = 0; q < 4; ++q) \
    _Pragma("unroll") for (int p = 0; p < 2; ++p) \
      acc[(mh) * 4 + q][(nh) * 2 + p] = __builtin_amdgcn_mfma_f32_16x16x32_bf16( \
          AF[kk][q], BF[kk][p], acc[(mh) * 4 + q][(nh) * 2 + p], 0, 0, 0); \
    __builtin_amdgcn_s_setprio(0); } while (0)

  f32x4 acc[8][4];
  #pragma unroll
  for (int m = 0; m < 8; ++m) {
    #pragma unroll
    for (int n = 0; n < 4; ++n) acc[m][n] = (f32x4){0.f, 0.f, 0.f, 0.f};
  }
  s16x8 afP[2][4], afQ[2][4];
  s16x8 b0[2][2], b1[2][2];

  STG(0, 1, 0, 0); STG(0, 0, 0, 0); STG(0, 0, 1, 0); STG(0, 1, 1, 0);
  STG(1, 1, 0, 1); STG(1, 0, 0, 1);
  VMW4(); BARR();
  RDA(afP, 0, 0); RDB(b0, 0, 0);

  const int nIter = nk >> 1;
  for (int it = 0; it < nIter; ++it) {
    const int t0 = 2 * it;
    STG(1, 0, 1, t0 + 1);
    MFMAQ(afP, b0, 0, 0);
    RDB(b1, 0, 1); BARR();
    STG(1, 1, 1, t0 + 1);
    MFMAQ(afP, b1, 0, 1);
    RDA(afQ, 0, 1); BARR();
    STG(0, 1, 0, t0 + 2);
    MFMAQ(afQ, b1, 1, 1);
    VMW2(); BARR();
    STG(0, 0, 0, t0 + 2);
    MFMAQ(afQ, b0, 1, 0);
    RDA(afP, 1, 0); RDB(b1, 1, 1); BARR();
    STG(0, 0, 1, t0 + 2);
    MFMAQ(afP, b1, 0, 1);
    RDB(b0, 1, 0); BARR();
    STG(0, 1, 1, t0 + 2);
    MFMAQ(afP, b0, 0, 0);
    RDA(afQ, 1, 1); BARR();
    STG(1, 1, 0, t0 + 3);
    MFMAQ(afQ, b0, 1, 0);
    VMW2(); BARR();
    STG(1, 0, 0, t0 + 3);
    MFMAQ(afQ, b1, 1, 1);
    RDA(afP, 0, 0); RDB(b0, 0, 0); BARR();
  }
  if (nk & 1) {
    MFMAQ(afP, b0, 0, 0);
    RDB(b1, 0, 1);
    MFMAQ(afP, b1, 0, 1);
    RDA(afQ, 0, 1);
    MFMAQ(afQ, b1, 1, 1);
    MFMAQ(afQ, b0, 1, 0);
  }

#undef STG
#undef LDA_
#undef LDB_
#undef BARR
#undef VMW2
#undef VMW4
#undef RDA
#undef RDB
#undef MFMAQ

  #pragma unroll
  for (int m = 0; m < 8; ++m) {
    #pragma unroll
    for (int i = 0; i < 4; ++i) {
      const int r = brow + wr * 128 + m * 16 + lgrp * 4 + i;
      #pragma unroll
      for (int n = 0; n < 4; ++n) {
        const int col = bcol + wc * 64 + n * 16 + lane15;
        float v = acc[m][n][i] + bias0[col];
        if (col < DD) o0[(size_t)r * DD + col] = f2bf(v);
        else          o1[(size_t)r * DD + (col - DD)] = f2bf(v);
      }
    }
  }
}

// ---------------- GEMM3: 128x128 tile, BK=64, counted-vmcnt pipeline ----------
// 4 waves = 2(M) x 2(N); per-wave 64x64 out; LDS 64 KiB (2 bufs); 2 blocks/CU.
// Per tile: STG(t+1) -> vmcnt(8) (t landed; t+1's 8 loads stay in flight) ->
// barrier -> ds_read(t) -> MFMA (lgkm dep forces read completion) -> barrier.
// Never vmcnt(0) in the main loop. Swizzle: verified 0-conflict path.
__global__ __launch_bounds__(256, 2)
void gemm3_128(const ushort_t* __restrict__ A, const ushort_t* __restrict__ W,
               int M, int N, int K,
               const float* __restrict__ bias, const float* __restrict__ resid,
               float* __restrict__ outf)
{
  __shared__ ushort_t lds[32768];   // 64 KiB: per buf 32KB = A[128][64] + B[128][64]
  const int tid = threadIdx.x;
  const int lane = tid & 63;
  const int wid = tid >> 6;
  const int wr = wid >> 1;          // 0..1
  const int wc = wid & 1;           // 0..1
  const int lane15 = lane & 15;
  const int lgrp = lane >> 4;
  const int rsw = (lane15 & 7) << 4;
  const int ntn = N >> 7;           // 8
  int bid = blockIdx.x;
  { const int cpx = (int)gridDim.x >> 3; bid = (bid & 7) * cpx + (bid >> 3); }
  const int brow = (bid / ntn) << 7;
  const int bcol = (bid % ntn) << 7;
  const int nk = K >> 6;            // 17
  const int sRow = tid >> 3;        // 0..31
  const int sCol = (tid & 7) << 4;  // bytes 0..112
  const char* ldsb = (const char*)lds;
  (void)M;

  f32x4 acc[4][4];
  #pragma unroll
  for (int q = 0; q < 4; ++q)
    #pragma unroll
    for (int p = 0; p < 4; ++p) acc[q][p] = (f32x4){0.f, 0.f, 0.f, 0.f};

#define STG3(bufb, kt) do { \
    _Pragma("unroll") \
    for (int j_ = 0; j_ < 4; ++j_) { \
      const int r_ = j_ * 32 + sRow; \
      load_lds16((const char*)(A + (size_t)(brow + r_) * K) + (kt) * 128 + (sCol ^ ((r_ & 7) << 4)), \
                 (char*)lds + (bufb) * 32768 + r_ * 128 + sCol); \
      load_lds16((const char*)(W + (size_t)(bcol + r_) * K) + (kt) * 128 + (sCol ^ ((r_ & 7) << 4)), \
                 (char*)lds + (bufb) * 32768 + 16384 + r_ * 128 + sCol); \
    } } while (0)
#define BARR3() asm volatile("s_barrier" ::: "memory")
#define VMW8() asm volatile("s_waitcnt vmcnt(8)" ::: "memory")
#define VMW0() asm volatile("s_waitcnt vmcnt(0)" ::: "memory")

  STG3(0, 0);     // 8 loads in flight

  for (int t = 0; t < nk; ++t) {
    const int cur = t & 1;
    if (t + 1 < nk) { STG3(cur ^ 1, t + 1); VMW8(); }
    else            { VMW0(); }
    BARR3();
    #pragma unroll
    for (int kk = 0; kk < 2; ++kk) {
      s16x8 af[4], bf[4];
      #pragma unroll
      for (int q = 0; q < 4; ++q)
        af[q] = *(const s16x8*)(ldsb + cur * 32768 +
                 (wr * 64 + q * 16 + lane15) * 128 + ((kk * 64 + lgrp * 16) ^ rsw));
      #pragma unroll
      for (int p = 0; p < 4; ++p)
        bf[p] = *(const s16x8*)(ldsb + cur * 32768 + 16384 +
                 (wc * 64 + p * 16 + lane15) * 128 + ((kk * 64 + lgrp * 16) ^ rsw));
      __builtin_amdgcn_s_setprio(1);
      #pragma unroll
      for (int q = 0; q < 4; ++q)
        #pragma unroll
        for (int p = 0; p < 4; ++p)
          acc[q][p] = __builtin_amdgcn_mfma_f32_16x16x32_bf16(af[q], bf[p], acc[q][p], 0, 0, 0);
      __builtin_amdgcn_s_setprio(0);
    }
    BARR3();   // MFMA's lgkm dep forced ds_reads complete; safe for next STG
  }
#undef STG3
#undef BARR3
#undef VMW8
#undef VMW0

  #pragma unroll
  for (int q = 0; q < 4; ++q) {
    #pragma unroll
    for (int i = 0; i < 4; ++i) {
      const int r = brow + wr * 64 + q * 16 + lgrp * 4 + i;
      #pragma unroll
      for (int p = 0; p < 4; ++p) {
        const int col = bcol + wc * 64 + p * 16 + lane15;
        outf[(size_t)r * DD + col] = acc[q][p][i] + bias[col] + resid[(size_t)r * DD + col];
      }
    }
  }
}

// ---------------- 128x128 2-phase GEMM, bf16 out (weight-prep fold) ----------------
__global__ __launch_bounds__(256)
void gemm128w(const ushort_t* __restrict__ A, const ushort_t* __restrict__ W,
              int M, int N, int K, ushort_t* __restrict__ o0)
{
  __shared__ ushort_t As[128 * 64];
  __shared__ ushort_t Bs[128 * 64];
  const int tid = threadIdx.x;
  const int lane = tid & 63;
  const int wid = tid >> 6;
  const int ntn = N >> 7;
  const int brow = (blockIdx.x / ntn) << 7;
  const int bcol = (blockIdx.x % ntn) << 7;
  const int wr = (wid >> 1) << 6;
  const int wc = (wid & 1) << 6;
  const int lane15 = lane & 15;
  const int lgrp = lane >> 4;
  (void)M;

  f32x4 acc[4][4];
  #pragma unroll
  for (int m = 0; m < 4; ++m)
    #pragma unroll
    for (int n = 0; n < 4; ++n)
      acc[m][n] = (f32x4){0.f, 0.f, 0.f, 0.f};

  const int r0 = tid >> 3;
  const int c0 = (tid & 7) << 3;
  const ushort_t* gA = A + (size_t)(brow + r0) * K + c0;
  const ushort_t* gW = W + (size_t)(bcol + r0) * K + c0;
  ushort_t* lA = &As[r0 * 64 + c0];
  ushort_t* lB = &Bs[r0 * 64 + c0];

  for (int k0 = 0; k0 < K; k0 += 64) {
    #pragma unroll
    for (int j = 0; j < 4; ++j) {
      load_lds16(gA + (size_t)(j * 32) * K + k0, lA + j * 32 * 64);
      load_lds16(gW + (size_t)(j * 32) * K + k0, lB + j * 32 * 64);
    }
    __syncthreads();
    #pragma unroll
    for (int kk = 0; kk < 2; ++kk) {
      s16x8 af[4], bfr[4];
      #pragma unroll
      for (int m = 0; m < 4; ++m)
        af[m] = *(const s16x8*)&As[(wr + m * 16 + lane15) * 64 + kk * 32 + lgrp * 8];
      #pragma unroll
      for (int n = 0; n < 4; ++n)
        bfr[n] = *(const s16x8*)&Bs[(wc + n * 16 + lane15) * 64 + kk * 32 + lgrp * 8];
      #pragma unroll
      for (int m = 0; m < 4; ++m)
        #pragma unroll
        for (int n = 0; n < 4; ++n)
          acc[m][n] = __builtin_amdgcn_mfma_f32_16x16x32_bf16(af[m], bfr[n], acc[m][n], 0, 0, 0);
    }
    __syncthreads();
  }

  #pragma unroll
  for (int m = 0; m < 4; ++m) {
    #pragma unroll
    for (int i = 0; i < 4; ++i) {
      const int r = brow + wr + m * 16 + lgrp * 4 + i;
      #pragma unroll
      for (int n = 0; n < 4; ++n) {
        const int col = bcol + wc + n * 16 + lane15;
        o0[(size_t)r * N + col] = f2bf(acc[m][n][i]);
      }
    }
  }
}

// ---------------- 128x128 2-phase GEMM: gates from xn (composite W/bias) --------
__global__ __launch_bounds__(256)
void gemm128g(const ushort_t* __restrict__ A, const ushort_t* __restrict__ W,
              int M, int N, int K,
              const float* __restrict__ gb, const float* __restrict__ alog,
              float* __restrict__ g0, float* __restrict__ g1, float* __restrict__ g2)
{
  __shared__ ushort_t As[128 * 64];
  __shared__ ushort_t Bs[128 * 64];
  const int tid = threadIdx.x;
  const int lane = tid & 63;
  const int wid = tid >> 6;
  const int ntn = N >> 7;
  const int brow = (blockIdx.x / ntn) << 7;
  const int bcol = (blockIdx.x % ntn) << 7;
  const int wr = (wid >> 1) << 6;
  const int wc = (wid & 1) << 6;
  const int lane15 = lane & 15;
  const int lgrp = lane >> 4;
  (void)M;

  f32x4 acc[4][4];
  #pragma unroll
  for (int m = 0; m < 4; ++m)
    #pragma unroll
    for (int n = 0; n < 4; ++n)
      acc[m][n] = (f32x4){0.f, 0.f, 0.f, 0.f};

  const int r0 = tid >> 3;
  const int c0 = (tid & 7) << 3;
  const ushort_t* gA = A + (size_t)(brow + r0) * K + c0;
  const ushort_t* gW = W + (size_t)(bcol + r0) * K + c0;
  ushort_t* lA = &As[r0 * 64 + c0];
  ushort_t* lB = &Bs[r0 * 64 + c0];

  for (int k0 = 0; k0 < K; k0 += 64) {
    #pragma unroll
    for (int j = 0; j < 4; ++j) {
      load_lds16(gA + (size_t)(j * 32) * K + k0, lA + j * 32 * 64);
      load_lds16(gW + (size_t)(j * 32) * K + k0, lB + j * 32 * 64);
    }
    __syncthreads();
    #pragma unroll
    for (int kk = 0; kk < 2; ++kk) {
      s16x8 af[4], bfr[4];
      #pragma unroll
      for (int m = 0; m < 4; ++m)
        af[m] = *(const s16x8*)&As[(wr + m * 16 + lane15) * 64 + kk * 32 + lgrp * 8];
      #pragma unroll
      for (int n = 0; n < 4; ++n)
        bfr[n] = *(const s16x8*)&Bs[(wc + n * 16 + lane15) * 64 + kk * 32 + lgrp * 8];
      #pragma unroll
      for (int m = 0; m < 4; ++m)
        #pragma unroll
        for (int n = 0; n < 4; ++n)
          acc[m][n] = __builtin_amdgcn_mfma_f32_16x16x32_bf16(af[m], bfr[n], acc[m][n], 0, 0, 0);
    }
    __syncthreads();
  }

  #pragma unroll
  for (int m = 0; m < 4; ++m) {
    #pragma unroll
    for (int i = 0; i < 4; ++i) {
      const int r = brow + wr + m * 16 + lgrp * 4 + i;
      #pragma unroll
      for (int n = 0; n < 4; ++n) {
        const int col = bcol + wc + n * 16 + lane15;
        float v = acc[m][n][i];
        if (col < 64) {
          float u = v + gb[col];
          float sp = (u > 20.f) ? u : log1pf(expf(u));
          g0[(size_t)r * 64 + col] = expf(-expf(alog[col]) * (sp + 1e-4f));
        } else if (col < 128) {
          g1[(size_t)r * 64 + (col - 64)] = tanhf(v + gb[col]);
        } else if (col < 192) {
          g2[(size_t)r * 64 + (col - 128)] = tanhf(v + gb[col]);
        }
      }
    }
  }
}

// ---------------- depthwise conv K=3 + tanh + *d -> mix[:, :D] ----------------
__global__ __launch_bounds__(256)
void conv_kernel(const ushort_t* __restrict__ xp, const float* __restrict__ cw,
                 const float* __restrict__ cb, const float* __restrict__ dvec,
                 ushort_t* __restrict__ mix)
{
  int idx = blockIdx.x * 256 + threadIdx.x;
  int row = idx >> 7;
  int d0 = (idx & 127) << 3;
  int t = row & (TT - 1);
  s16x8 cur = *(const s16x8*)&xp[(size_t)row * DD + d0];
  s16x8 prv; s16x8 nxt;
  #pragma unroll
  for (int j = 0; j < 8; ++j) { prv[j] = 0; nxt[j] = 0; }
  if (t > 0)      prv = *(const s16x8*)&xp[(size_t)(row - 1) * DD + d0];
  if (t < TT - 1) nxt = *(const s16x8*)&xp[(size_t)(row + 1) * DD + d0];
  float wv[24];
  #pragma unroll
  for (int j = 0; j < 6; ++j) *(float4*)&wv[j * 4] = *(const float4*)&cw[d0 * 3 + j * 4];
  float cbv[8], dv[8];
  *(float4*)&cbv[0] = *(const float4*)&cb[d0];
  *(float4*)&cbv[4] = *(const float4*)&cb[d0 + 4];
  *(float4*)&dv[0]  = *(const float4*)&dvec[d0];
  *(float4*)&dv[4]  = *(const float4*)&dvec[d0 + 4];
  s16x8 o;
  #pragma unroll
  for (int j = 0; j < 8; ++j) {
    float acc = cbv[j] + bf2f((ushort_t)prv[j]) * wv[j * 3]
              + bf2f((ushort_t)cur[j]) * wv[j * 3 + 1]
              + bf2f((ushort_t)nxt[j]) * wv[j * 3 + 2];
    o[j] = (short)f2bf(tanhf(acc) * dv[j]);
  }
  *(s16x8*)&mix[(size_t)row * 1088 + d0] = o;
}

// ---------------- chunked scan ----------------
__global__ void scanA_kernel(const float* __restrict__ dec, const float* __restrict__ bb,
                             float* __restrict__ P, float* __restrict__ Q)
{
  int b = blockIdx.x >> 6, ci = blockIdx.x & 63, s = threadIdx.x;
  size_t base = (((size_t)b * TT) + ci * 64) * 64 + s;
  float p = 1.f, q = 0.f;
  #pragma unroll 4
  for (int t = 0; t < 64; ++t) {
    float d = dec[base + (size_t)t * 64];
    float w = bb[base + (size_t)t * 64];
    q = q * d + w; p *= d;
  }
  int o = (b * 64 + ci) * 64 + s;
  P[o] = p; Q[o] = q;
}

__global__ void scanB_kernel(const float* __restrict__ P, const float* __restrict__ Q,
                             float* __restrict__ I)
{
  int b = blockIdx.x, s = threadIdx.x;
  float pv[64], qv[64];
  #pragma unroll
  for (int ci = 0; ci < 64; ++ci) {
    int o = (b * 64 + ci) * 64 + s;
    pv[ci] = P[o]; qv[ci] = Q[o];
  }
  float st = 0.f;
  #pragma unroll
  for (int ci = 0; ci < 64; ++ci) {
    int o = (b * 64 + ci) * 64 + s;
    I[o] = st;
    st = st * pv[ci] + qv[ci];
  }
}

__global__ void scanC_kernel(const float* __restrict__ dec, const float* __restrict__ bb,
                             const float* __restrict__ cc, const float* __restrict__ I,
                             ushort_t* __restrict__ mix)
{
  int b = blockIdx.x >> 6, ci = blockIdx.x & 63, s = threadIdx.x;
  size_t base = (((size_t)b * TT) + ci * 64) * 64 + s;
  float st = I[(b * 64 + ci) * 64 + s];
  size_t mrow = (size_t)b * TT + ci * 64;
  #pragma unroll 4
  for (int t = 0; t < 64; ++t) {
    size_t o = base + (size_t)t * 64;
    st = st * dec[o] + bb[o];
    mix[(mrow + t) * 1088 + 1024 + s] = (ushort_t)f2bf(cc[o] * st);
  }
}

// ---------------- launch ----------------
extern "C" void kernel_launch(void* const* d_in, const int* in_sizes, int n_in,
                              void* d_out, int out_size, void* d_ws, size_t ws_size,
                              hipStream_t stream)
{
  (void)in_sizes; (void)n_in; (void)out_size; (void)ws_size;
  const float* x      = (const float*)d_in[0];
  const float* norm_w = (const float*)d_in[1];
  const float* norm_b = (const float*)d_in[2];
  const float* in_w   = (const float*)d_in[3];
  const float* in_b   = (const float*)d_in[4];
  const float* conv_w = (const float*)d_in[5];
  const float* conv_b = (const float*)d_in[6];
  const float* dt_w   = (const float*)d_in[7];
  const float* dt_b   = (const float*)d_in[8];
  const float* b_w    = (const float*)d_in[9];
  const float* b_b    = (const float*)d_in[10];
  const float* c_w    = (const float*)d_in[11];
  const float* c_b    = (const float*)d_in[12];
  const float* a_log  = (const float*)d_in[13];
  const float* dvec   = (const float*)d_in[14];
  const float* out_w  = (const float*)d_in[15];
  const float* out_b  = (const float*)d_in[16];
  float* out = (float*)d_out;

  char* p = (char*)d_ws;
  ushort_t* mix    = (ushort_t*)p;               // NN x 1088 bf16 (xn aliases head)
  ushort_t* xn     = mix;
  p += 71303168;
  ushort_t* xproj  = (ushort_t*)p; p += 67108864;
  char*     zreg   = p;            p += 67108864; // gates + fold scratch
  ushort_t* w1_bf  = (ushort_t*)p; p += 4194304;  // 1024x1024 bf16 (xproj weight)
  ushort_t* w3     = (ushort_t*)p; p += 524288;   // 256x1024 bf16 (orig gate W, padded)
  ushort_t* outw_bf= (ushort_t*)p; p += 2228224;
  float* P = (float*)p; p += 131072;
  float* Q = (float*)p; p += 131072;
  float* I = (float*)p; p += 131072;

  float* gdec = (float*)zreg;                        // NN x 64 f32
  float* gbb  = (float*)(zreg + 8388608);
  float* gcc  = (float*)(zreg + 16777216);
  ushort_t* inw2t  = (ushort_t*)(zreg + 33554432);   // 1024x1024 bf16 (dead after fold)
  float*    gb     = (float*)(zreg + 37748736);      // 192 f32 composite bias
  ushort_t* wgates = (ushort_t*)(zreg + 41943040);   // 256x1024 bf16 composite gate W

  // --- weight prep ---
  cvt_kernel<<<1024, 256, 0, stream>>>(in_w, w1_bf, 1048576);        // W1 (rows 0..1023)
  cvt_kernel<<<1088, 256, 0, stream>>>(out_w, outw_bf, 1114112);
  tpose_kernel<<<256, 256, 0, stream>>>(in_w + 1048576, inw2t);      // in_w2^T
  w3pad_kernel<<<256, 256, 0, stream>>>(dt_w, b_w, c_w, w3);
  gemm128w<<<16, 256, 0, stream>>>(w3, inw2t, 256, 1024, 1024, wgates);  // Wg = W3 @ W2
  gbias_kernel<<<192, 64, 0, stream>>>(dt_w, b_w, c_w, dt_b, b_b, c_b, in_b, gb);

  ln_kernel<<<8192, 256, 0, stream>>>(x, norm_w, norm_b, xn);

  // GEMM1a: xproj = xn @ W1^T + in_b[:1024]   (M=32768, N=1024, K=1024)
  gemm256<0><<<(NN / 256) * (1024 / 256), 512, 0, stream>>>(
      xn, w1_bf, NN, 1024, 1024, in_b, xproj, nullptr);

  // GEMM2': gates = xn @ Wg^T + gb  (runs BEFORE conv overwrites mix/xn)
  gemm128g<<<(NN / 128) * (256 / 128), 256, 0, stream>>>(
      xn, wgates, NN, 256, 1024, gb, a_log, gdec, gbb, gcc);

  conv_kernel<<<NN * 128 / 256, 256, 0, stream>>>(xproj, conv_w, conv_b, dvec, mix);

  scanA_kernel<<<512, 64, 0, stream>>>(gdec, gbb, P, Q);
  scanB_kernel<<<8, 64, 0, stream>>>(P, Q, I);
  scanC_kernel<<<512, 64, 0, stream>>>(gdec, gbb, gcc, I, mix);

  // GEMM3: out = mix @ out_w^T + out_b + x  (K=1088, nk=17; counted-vmcnt pipeline)
  gemm3_128<<<(NN / 128) * (1024 / 128), 256, 0, stream>>>(
      mix, outw_bf, NN, 1024, 1088, out_b, x, out);
}

// Round 15
// 386.420 us; speedup vs baseline: 1.0478x; 1.0176x over previous
//
#include <hip/hip_runtime.h>

#define TT 4096
#define DD 1024
#define NN 32768   // B*T rows

typedef short s16x8 __attribute__((ext_vector_type(8)));
typedef float f32x4 __attribute__((ext_vector_type(4)));
typedef unsigned short ushort_t;

__device__ __forceinline__ unsigned short f2bf(float f) {
  unsigned u = __float_as_uint(f);
  u += 0x7FFFu + ((u >> 16) & 1u);
  return (unsigned short)(u >> 16);
}
__device__ __forceinline__ float bf2f(unsigned short h) {
  return __uint_as_float(((unsigned)h) << 16);
}
__device__ __forceinline__ void load_lds16(const void* g, void* l) {
  __builtin_amdgcn_global_load_lds(
      (const __attribute__((address_space(1))) unsigned int*)g,
      (__attribute__((address_space(3))) unsigned int*)l, 16, 0, 0);
}

// ---------------- prep1: all weight conversions in one launch ----------------
// blocks [0,1024): in_w -> w1_bf ; [1024,2112): out_w -> outw_bf ;
// [2112,2368): w3pad ; [2368,2624): tpose of in_w2 -> inw2t
__global__ __launch_bounds__(256)
void prep1_kernel(const float* __restrict__ in_w, const float* __restrict__ out_w,
                  const float* __restrict__ dt_w, const float* __restrict__ b_w,
                  const float* __restrict__ c_w,
                  ushort_t* __restrict__ w1_bf, ushort_t* __restrict__ outw_bf,
                  ushort_t* __restrict__ w3, ushort_t* __restrict__ inw2t)
{
  __shared__ float tile[64][65];
  int blk = blockIdx.x, tid = threadIdx.x;
  if (blk < 1024) {
    int i = (blk * 256 + tid) * 4;
    float4 v = *(const float4*)&in_w[i];
    ushort4 o; o.x = f2bf(v.x); o.y = f2bf(v.y); o.z = f2bf(v.z); o.w = f2bf(v.w);
    *(ushort4*)&w1_bf[i] = o;
  } else if (blk < 2112) {
    int i = ((blk - 1024) * 256 + tid) * 4;
    if (i < 1114112) {
      float4 v = *(const float4*)&out_w[i];
      ushort4 o; o.x = f2bf(v.x); o.y = f2bf(v.y); o.z = f2bf(v.z); o.w = f2bf(v.w);
      *(ushort4*)&outw_bf[i] = o;
    }
  } else if (blk < 2368) {
    int e = ((blk - 2112) * 256 + tid) * 4;
    int row = e >> 10, col = e & 1023;
    float4 v; v.x = 0.f; v.y = 0.f; v.z = 0.f; v.w = 0.f;
    if (row < 64)       v = *(const float4*)&dt_w[(row << 10) + col];
    else if (row < 128) v = *(const float4*)&b_w[((row - 64) << 10) + col];
    else if (row < 192) v = *(const float4*)&c_w[((row - 128) << 10) + col];
    ushort4 o; o.x = f2bf(v.x); o.y = f2bf(v.y); o.z = f2bf(v.z); o.w = f2bf(v.w);
    *(ushort4*)&w3[e] = o;
  } else {
    int b2 = blk - 2368;
    int bx = b2 & 15, by = b2 >> 4;
    int tx = tid & 63, ty0 = tid >> 6;
    const float* src = in_w + 1048576;
    #pragma unroll
    for (int i = 0; i < 16; ++i) {
      int ty = ty0 * 16 + i;
      tile[ty][tx] = src[(size_t)(by * 64 + ty) * 1024 + bx * 64 + tx];
    }
    __syncthreads();
    #pragma unroll
    for (int i = 0; i < 16; ++i) {
      int ty = ty0 * 16 + i;
      inw2t[(size_t)(bx * 64 + ty) * 1024 + by * 64 + tx] = f2bf(tile[tx][ty]);
    }
  }
}

// ---------------- prep2: Wg = w3 @ inw2t (blocks 0..15) + gbias (blocks 16..63) --
__global__ __launch_bounds__(256)
void prep2_kernel(const ushort_t* __restrict__ w3, const ushort_t* __restrict__ inw2t,
                  ushort_t* __restrict__ wgates,
                  const float* __restrict__ dt_w, const float* __restrict__ b_w,
                  const float* __restrict__ c_w, const float* __restrict__ dt_b,
                  const float* __restrict__ b_b, const float* __restrict__ c_b,
                  const float* __restrict__ in_b, float* __restrict__ gb)
{
  __shared__ ushort_t As[128 * 64];
  __shared__ ushort_t Bs[128 * 64];
  const int tid = threadIdx.x;
  if (blockIdx.x >= 16) {   // gbias: composite gate bias
    int i = (blockIdx.x - 16) * 4 + (tid >> 6);
    int lane = tid & 63;
    const float* wr = i < 64 ? dt_w + (size_t)i * 1024
                    : i < 128 ? b_w + (size_t)(i - 64) * 1024
                              : c_w + (size_t)(i - 128) * 1024;
    float s = 0.f;
    for (int j = lane; j < 1024; j += 64) s += wr[j] * in_b[1024 + j];
    #pragma unroll
    for (int off = 32; off; off >>= 1) s += __shfl_xor(s, off, 64);
    if (lane == 0) {
      float bb = i < 64 ? dt_b[i] : i < 128 ? b_b[i - 64] : c_b[i - 128];
      gb[i] = s + bb;
    }
    return;
  }
  // gemm128w: 256x1024x1024, bf16 out
  const int K = 1024, N = 1024;
  const int bid = blockIdx.x;
  const int lane = tid & 63;
  const int wid = tid >> 6;
  const int brow = (bid / 8) << 7;
  const int bcol = (bid % 8) << 7;
  const int wr = (wid >> 1) << 6;
  const int wc = (wid & 1) << 6;
  const int lane15 = lane & 15;
  const int lgrp = lane >> 4;

  f32x4 acc[4][4];
  #pragma unroll
  for (int m = 0; m < 4; ++m)
    #pragma unroll
    for (int n = 0; n < 4; ++n)
      acc[m][n] = (f32x4){0.f, 0.f, 0.f, 0.f};

  const int r0 = tid >> 3;
  const int c0 = (tid & 7) << 3;
  const ushort_t* gA = w3 + (size_t)(brow + r0) * K + c0;
  const ushort_t* gW = inw2t + (size_t)(bcol + r0) * K + c0;
  ushort_t* lA = &As[r0 * 64 + c0];
  ushort_t* lB = &Bs[r0 * 64 + c0];

  for (int k0 = 0; k0 < K; k0 += 64) {
    #pragma unroll
    for (int j = 0; j < 4; ++j) {
      load_lds16(gA + (size_t)(j * 32) * K + k0, lA + j * 32 * 64);
      load_lds16(gW + (size_t)(j * 32) * K + k0, lB + j * 32 * 64);
    }
    __syncthreads();
    #pragma unroll
    for (int kk = 0; kk < 2; ++kk) {
      s16x8 af[4], bfr[4];
      #pragma unroll
      for (int m = 0; m < 4; ++m)
        af[m] = *(const s16x8*)&As[(wr + m * 16 + lane15) * 64 + kk * 32 + lgrp * 8];
      #pragma unroll
      for (int n = 0; n < 4; ++n)
        bfr[n] = *(const s16x8*)&Bs[(wc + n * 16 + lane15) * 64 + kk * 32 + lgrp * 8];
      #pragma unroll
      for (int m = 0; m < 4; ++m)
        #pragma unroll
        for (int n = 0; n < 4; ++n)
          acc[m][n] = __builtin_amdgcn_mfma_f32_16x16x32_bf16(af[m], bfr[n], acc[m][n], 0, 0, 0);
    }
    __syncthreads();
  }

  #pragma unroll
  for (int m = 0; m < 4; ++m) {
    #pragma unroll
    for (int i = 0; i < 4; ++i) {
      const int r = brow + wr + m * 16 + lgrp * 4 + i;
      #pragma unroll
      for (int n = 0; n < 4; ++n) {
        const int col = bcol + wc + n * 16 + lane15;
        wgates[(size_t)r * N + col] = f2bf(acc[m][n][i]);
      }
    }
  }
}

// ---------------- LayerNorm -> bf16 ----------------
__global__ __launch_bounds__(256)
void ln_kernel(const float* __restrict__ x, const float* __restrict__ w,
               const float* __restrict__ bv, ushort_t* __restrict__ xn)
{
  int row = blockIdx.x * 4 + (threadIdx.x >> 6);
  int lane = threadIdx.x & 63;
  const float* xr = x + (size_t)row * DD;
  float4 v[4];
  float s = 0.f, ss = 0.f;
  #pragma unroll
  for (int j = 0; j < 4; ++j) {
    v[j] = *(const float4*)&xr[j * 256 + lane * 4];
    s  += v[j].x + v[j].y + v[j].z + v[j].w;
    ss += v[j].x * v[j].x + v[j].y * v[j].y + v[j].z * v[j].z + v[j].w * v[j].w;
  }
  #pragma unroll
  for (int off = 32; off > 0; off >>= 1) {
    s  += __shfl_xor(s, off, 64);
    ss += __shfl_xor(ss, off, 64);
  }
  float mean = s * (1.f / 1024.f);
  float var  = ss * (1.f / 1024.f) - mean * mean;
  float rinv = rsqrtf(var + 1e-5f);
  #pragma unroll
  for (int j = 0; j < 4; ++j) {
    int c = j * 256 + lane * 4;
    float4 wv = *(const float4*)&w[c];
    float4 bb = *(const float4*)&bv[c];
    ushort4 o;
    o.x = f2bf((v[j].x - mean) * rinv * wv.x + bb.x);
    o.y = f2bf((v[j].y - mean) * rinv * wv.y + bb.y);
    o.z = f2bf((v[j].z - mean) * rinv * wv.z + bb.z);
    o.w = f2bf((v[j].w - mean) * rinv * wv.w + bb.w);
    *(ushort4*)&xn[(size_t)row * DD + c] = o;
  }
}

// ---------------- 256x256 8-phase GEMM (round-4 verified schedule) ----------------
template<int EP>
__global__ __launch_bounds__(512, 2)
void gemm256(const ushort_t* __restrict__ A, const ushort_t* __restrict__ W,
             int M, int N, int K,
             const float* __restrict__ bias0,
             ushort_t* __restrict__ o0, ushort_t* __restrict__ o1)
{
  __shared__ ushort_t lds[65536];   // 128 KiB
  const int tid = threadIdx.x;
  const int lane = tid & 63;
  const int wid = tid >> 6;
  const int wr = wid >> 2;          // 0..1
  const int wc = wid & 3;           // 0..3
  const int lane15 = lane & 15;
  const int lgrp = lane >> 4;
  const int rsw = (lane15 & 7) << 4;
  const int ntn = N >> 8;
  int bid = blockIdx.x;
  { const int cpx = (int)gridDim.x >> 3; bid = (bid & 7) * cpx + (bid >> 3); }
  const int brow = (bid / ntn) << 8;
  const int bcol = (bid % ntn) << 8;
  const int nk = K >> 6;
  const int sRow = tid >> 3;        // 0..63
  const int sCol = (tid & 7) << 4;  // bytes 0..112
  const char* ldsb = (const char*)lds;
  (void)M;

#define STG(bufb, isB, h, kt) do { \
    const int ktc_ = (kt) < nk ? (kt) : nk - 1; \
    const ushort_t* gsrc_ = (isB) ? W : A; \
    const int rowb_ = ((isB) ? bcol : brow) + (h) * 128; \
    _Pragma("unroll") \
    for (int j_ = 0; j_ < 2; ++j_) { \
      const int r_ = j_ * 64 + sRow; \
      load_lds16((const char*)(gsrc_ + (size_t)(rowb_ + r_) * K) + ktc_ * 128 + (sCol ^ ((r_ & 7) << 4)), \
                 (char*)lds + (bufb) * 65536 + (isB) * 32768 + (h) * 16384 + r_ * 128 + sCol); \
    } } while (0)

#define LDA_(bufb, m, kk) \
  (*(const s16x8*)(ldsb + (bufb) * 65536 + wr * 16384 + ((m) * 16 + lane15) * 128 + (((kk) * 64 + lgrp * 16) ^ rsw)))
#define LDB_(bufb, n, kk) \
  (*(const s16x8*)(ldsb + (bufb) * 65536 + 32768 + (wc >> 1) * 16384 + ((wc & 1) * 64 + (n) * 16 + lane15) * 128 + (((kk) * 64 + lgrp * 16) ^ rsw)))

#define BARR() asm volatile("s_barrier" ::: "memory")
#define VMW2() asm volatile("s_waitcnt vmcnt(2)" ::: "memory")
#define VMW4() asm volatile("s_waitcnt vmcnt(4)" ::: "memory")

#define RDA(dst, bufb, mh) do { \
    _Pragma("unroll") for (int kk = 0; kk < 2; ++kk) \
    _Pragma("unroll") for (int q = 0; q < 4; ++q) \
      dst[kk][q] = LDA_(bufb, (mh) * 4 + q, kk); } while (0)
#define RDB(dst, bufb, nh) do { \
    _Pragma("unroll") for (int kk = 0; kk < 2; ++kk) \
    _Pragma("unroll") for (int p = 0; p < 2; ++p) \
      dst[kk][p] = LDB_(bufb, (nh) * 2 + p, kk); } while (0)

#define MFMAQ(AF, BF, mh, nh) do { \
    __builtin_amdgcn_s_setprio(1); \
    _Pragma("unroll") for (int kk = 0; kk < 2; ++kk) \
    _Pragma("unroll") for (int q = 0; q < 4; ++q) \
    _Pragma("unroll") for (int p = 0; p < 2; ++p) \
      acc[(mh) * 4 + q][(nh) * 2 + p] = __builtin_amdgcn_mfma_f32_16x16x32_bf16( \
          AF[kk][q], BF[kk][p], acc[(mh) * 4 + q][(nh) * 2 + p], 0, 0, 0); \
    __builtin_amdgcn_s_setprio(0); } while (0)

  f32x4 acc[8][4];
  #pragma unroll
  for (int m = 0; m < 8; ++m) {
    #pragma unroll
    for (int n = 0; n < 4; ++n) acc[m][n] = (f32x4){0.f, 0.f, 0.f, 0.f};
  }
  s16x8 afP[2][4], afQ[2][4];
  s16x8 b0[2][2], b1[2][2];

  STG(0, 1, 0, 0); STG(0, 0, 0, 0); STG(0, 0, 1, 0); STG(0, 1, 1, 0);
  STG(1, 1, 0, 1); STG(1, 0, 0, 1);
  VMW4(); BARR();
  RDA(afP, 0, 0); RDB(b0, 0, 0);

  const int nIter = nk >> 1;
  for (int it = 0; it < nIter; ++it) {
    const int t0 = 2 * it;
    STG(1, 0, 1, t0 + 1);
    MFMAQ(afP, b0, 0, 0);
    RDB(b1, 0, 1); BARR();
    STG(1, 1, 1, t0 + 1);
    MFMAQ(afP, b1, 0, 1);
    RDA(afQ, 0, 1); BARR();
    STG(0, 1, 0, t0 + 2);
    MFMAQ(afQ, b1, 1, 1);
    VMW2(); BARR();
    STG(0, 0, 0, t0 + 2);
    MFMAQ(afQ, b0, 1, 0);
    RDA(afP, 1, 0); RDB(b1, 1, 1); BARR();
    STG(0, 0, 1, t0 + 2);
    MFMAQ(afP, b1, 0, 1);
    RDB(b0, 1, 0); BARR();
    STG(0, 1, 1, t0 + 2);
    MFMAQ(afP, b0, 0, 0);
    RDA(afQ, 1, 1); BARR();
    STG(1, 1, 0, t0 + 3);
    MFMAQ(afQ, b0, 1, 0);
    VMW2(); BARR();
    STG(1, 0, 0, t0 + 3);
    MFMAQ(afQ, b1, 1, 1);
    RDA(afP, 0, 0); RDB(b0, 0, 0); BARR();
  }
  if (nk & 1) {
    MFMAQ(afP, b0, 0, 0);
    RDB(b1, 0, 1);
    MFMAQ(afP, b1, 0, 1);
    RDA(afQ, 0, 1);
    MFMAQ(afQ, b1, 1, 1);
    MFMAQ(afQ, b0, 1, 0);
  }

#undef STG
#undef LDA_
#undef LDB_
#undef BARR
#undef VMW2
#undef VMW4
#undef RDA
#undef RDB
#undef MFMAQ

  #pragma unroll
  for (int m = 0; m < 8; ++m) {
    #pragma unroll
    for (int i = 0; i < 4; ++i) {
      const int r = brow + wr * 128 + m * 16 + lgrp * 4 + i;
      #pragma unroll
      for (int n = 0; n < 4; ++n) {
        const int col = bcol + wc * 64 + n * 16 + lane15;
        float v = acc[m][n][i] + bias0[col];
        if (col < DD) o0[(size_t)r * DD + col] = f2bf(v);
        else          o1[(size_t)r * DD + (col - DD)] = f2bf(v);
      }
    }
  }
}

// ---------------- GEMM3 v2: 128x256 tile, BK=64, 8 waves, 96 KiB LDS -----------
// ntn=4 -> A-panel re-fetch halves vs 128x128. Counted vmcnt(6); 0-conflict swizzle.
__global__ __launch_bounds__(512, 1)
void gemm3_v2(const ushort_t* __restrict__ A, const ushort_t* __restrict__ W,
              int M, int N, int K,
              const float* __restrict__ bias, const float* __restrict__ resid,
              float* __restrict__ outf)
{
  __shared__ ushort_t lds[49152];   // 96 KiB: per buf 48KB = A[128][64] + B[256][64]
  const int tid = threadIdx.x;
  const int lane = tid & 63;
  const int wid = tid >> 6;
  const int wr2 = wid >> 2;         // 0..1 (64-row half)
  const int wc4 = wid & 3;          // 0..3 (64-col quarter)
  const int lane15 = lane & 15;
  const int lgrp = lane >> 4;
  const int rsw = (lane15 & 7) << 4;
  const int ntn = N >> 8;           // 4
  int bid = blockIdx.x;
  { const int cpx = (int)gridDim.x >> 3; bid = (bid & 7) * cpx + (bid >> 3); }
  const int brow = (bid / ntn) << 7;    // 128-row tile
  const int bcol = (bid % ntn) << 8;    // 256-col tile
  const int nk = K >> 6;                // 17
  const int sRow = tid >> 3;            // 0..63
  const int sCol = (tid & 7) << 4;      // bytes 0..112
  const char* ldsb = (const char*)lds;
  (void)M;

  f32x4 acc[4][4];
  #pragma unroll
  for (int q = 0; q < 4; ++q)
    #pragma unroll
    for (int p = 0; p < 4; ++p) acc[q][p] = (f32x4){0.f, 0.f, 0.f, 0.f};

#define STG3(bufb, kt) do { \
    _Pragma("unroll") \
    for (int j_ = 0; j_ < 2; ++j_) { \
      const int r_ = j_ * 64 + sRow; \
      load_lds16((const char*)(A + (size_t)(brow + r_) * K) + (kt) * 128 + (sCol ^ ((r_ & 7) << 4)), \
                 (char*)lds + (bufb) * 49152 + r_ * 128 + sCol); \
    } \
    _Pragma("unroll") \
    for (int j_ = 0; j_ < 4; ++j_) { \
      const int r_ = j_ * 64 + sRow; \
      load_lds16((const char*)(W + (size_t)(bcol + r_) * K) + (kt) * 128 + (sCol ^ ((r_ & 7) << 4)), \
                 (char*)lds + (bufb) * 49152 + 16384 + r_ * 128 + sCol); \
    } } while (0)
#define BARR3() asm volatile("s_barrier" ::: "memory")
#define VMW6() asm volatile("s_waitcnt vmcnt(6)" ::: "memory")
#define VMW0() asm volatile("s_waitcnt vmcnt(0)" ::: "memory")

  STG3(0, 0);     // 6 loads/thread in flight

  for (int t = 0; t < nk; ++t) {
    const int cur = t & 1;
    if (t + 1 < nk) { STG3(cur ^ 1, t + 1); VMW6(); }
    else            { VMW0(); }
    BARR3();
    #pragma unroll
    for (int kk = 0; kk < 2; ++kk) {
      s16x8 af[4], bf[4];
      #pragma unroll
      for (int q = 0; q < 4; ++q)
        af[q] = *(const s16x8*)(ldsb + cur * 49152 +
                 (wr2 * 64 + q * 16 + lane15) * 128 + ((kk * 64 + lgrp * 16) ^ rsw));
      #pragma unroll
      for (int p = 0; p < 4; ++p)
        bf[p] = *(const s16x8*)(ldsb + cur * 49152 + 16384 +
                 (wc4 * 64 + p * 16 + lane15) * 128 + ((kk * 64 + lgrp * 16) ^ rsw));
      __builtin_amdgcn_s_setprio(1);
      #pragma unroll
      for (int q = 0; q < 4; ++q)
        #pragma unroll
        for (int p = 0; p < 4; ++p)
          acc[q][p] = __builtin_amdgcn_mfma_f32_16x16x32_bf16(af[q], bf[p], acc[q][p], 0, 0, 0);
      __builtin_amdgcn_s_setprio(0);
    }
    BARR3();
  }
#undef STG3
#undef BARR3
#undef VMW6
#undef VMW0

  #pragma unroll
  for (int q = 0; q < 4; ++q) {
    #pragma unroll
    for (int i = 0; i < 4; ++i) {
      const int r = brow + wr2 * 64 + q * 16 + lgrp * 4 + i;
      #pragma unroll
      for (int p = 0; p < 4; ++p) {
        const int col = bcol + wc4 * 64 + p * 16 + lane15;
        outf[(size_t)r * DD + col] = acc[q][p][i] + bias[col] + resid[(size_t)r * DD + col];
      }
    }
  }
}

// ---------------- 128x128 2-phase GEMM: gates from xn (composite W/bias) --------
__global__ __launch_bounds__(256)
void gemm128g(const ushort_t* __restrict__ A, const ushort_t* __restrict__ W,
              int M, int N, int K,
              const float* __restrict__ gb, const float* __restrict__ alog,
              float* __restrict__ g0, float* __restrict__ g1, float* __restrict__ g2)
{
  __shared__ ushort_t As[128 * 64];
  __shared__ ushort_t Bs[128 * 64];
  const int tid = threadIdx.x;
  const int lane = tid & 63;
  const int wid = tid >> 6;
  const int ntn = N >> 7;
  const int brow = (blockIdx.x / ntn) << 7;
  const int bcol = (blockIdx.x % ntn) << 7;
  const int wr = (wid >> 1) << 6;
  const int wc = (wid & 1) << 6;
  const int lane15 = lane & 15;
  const int lgrp = lane >> 4;
  (void)M;

  f32x4 acc[4][4];
  #pragma unroll
  for (int m = 0; m < 4; ++m)
    #pragma unroll
    for (int n = 0; n < 4; ++n)
      acc[m][n] = (f32x4){0.f, 0.f, 0.f, 0.f};

  const int r0 = tid >> 3;
  const int c0 = (tid & 7) << 3;
  const ushort_t* gA = A + (size_t)(brow + r0) * K + c0;
  const ushort_t* gW = W + (size_t)(bcol + r0) * K + c0;
  ushort_t* lA = &As[r0 * 64 + c0];
  ushort_t* lB = &Bs[r0 * 64 + c0];

  for (int k0 = 0; k0 < K; k0 += 64) {
    #pragma unroll
    for (int j = 0; j < 4; ++j) {
      load_lds16(gA + (size_t)(j * 32) * K + k0, lA + j * 32 * 64);
      load_lds16(gW + (size_t)(j * 32) * K + k0, lB + j * 32 * 64);
    }
    __syncthreads();
    #pragma unroll
    for (int kk = 0; kk < 2; ++kk) {
      s16x8 af[4], bfr[4];
      #pragma unroll
      for (int m = 0; m < 4; ++m)
        af[m] = *(const s16x8*)&As[(wr + m * 16 + lane15) * 64 + kk * 32 + lgrp * 8];
      #pragma unroll
      for (int n = 0; n < 4; ++n)
        bfr[n] = *(const s16x8*)&Bs[(wc + n * 16 + lane15) * 64 + kk * 32 + lgrp * 8];
      #pragma unroll
      for (int m = 0; m < 4; ++m)
        #pragma unroll
        for (int n = 0; n < 4; ++n)
          acc[m][n] = __builtin_amdgcn_mfma_f32_16x16x32_bf16(af[m], bfr[n], acc[m][n], 0, 0, 0);
    }
    __syncthreads();
  }

  #pragma unroll
  for (int m = 0; m < 4; ++m) {
    #pragma unroll
    for (int i = 0; i < 4; ++i) {
      const int r = brow + wr + m * 16 + lgrp * 4 + i;
      #pragma unroll
      for (int n = 0; n < 4; ++n) {
        const int col = bcol + wc + n * 16 + lane15;
        float v = acc[m][n][i];
        if (col < 64) {
          float u = v + gb[col];
          float sp = (u > 20.f) ? u : log1pf(expf(u));
          g0[(size_t)r * 64 + col] = expf(-expf(alog[col]) * (sp + 1e-4f));
        } else if (col < 128) {
          g1[(size_t)r * 64 + (col - 64)] = tanhf(v + gb[col]);
        } else if (col < 192) {
          g2[(size_t)r * 64 + (col - 128)] = tanhf(v + gb[col]);
        }
      }
    }
  }
}

// ---------------- conv (blocks 0..16383) + scanC (blocks 16384..16511) ----------
__global__ __launch_bounds__(256)
void convscanC_kernel(const ushort_t* __restrict__ xp, const float* __restrict__ cw,
                      const float* __restrict__ cb, const float* __restrict__ dvec,
                      const float* __restrict__ dec, const float* __restrict__ bb,
                      const float* __restrict__ cc, const float* __restrict__ I,
                      ushort_t* __restrict__ mix)
{
  if (blockIdx.x < 16384) {
    int idx = blockIdx.x * 256 + threadIdx.x;
    int row = idx >> 7;
    int d0 = (idx & 127) << 3;
    int t = row & (TT - 1);
    s16x8 cur = *(const s16x8*)&xp[(size_t)row * DD + d0];
    s16x8 prv; s16x8 nxt;
    #pragma unroll
    for (int j = 0; j < 8; ++j) { prv[j] = 0; nxt[j] = 0; }
    if (t > 0)      prv = *(const s16x8*)&xp[(size_t)(row - 1) * DD + d0];
    if (t < TT - 1) nxt = *(const s16x8*)&xp[(size_t)(row + 1) * DD + d0];
    float wv[24];
    #pragma unroll
    for (int j = 0; j < 6; ++j) *(float4*)&wv[j * 4] = *(const float4*)&cw[d0 * 3 + j * 4];
    float cbv[8], dv[8];
    *(float4*)&cbv[0] = *(const float4*)&cb[d0];
    *(float4*)&cbv[4] = *(const float4*)&cb[d0 + 4];
    *(float4*)&dv[0]  = *(const float4*)&dvec[d0];
    *(float4*)&dv[4]  = *(const float4*)&dvec[d0 + 4];
    s16x8 o;
    #pragma unroll
    for (int j = 0; j < 8; ++j) {
      float acc = cbv[j] + bf2f((ushort_t)prv[j]) * wv[j * 3]
                + bf2f((ushort_t)cur[j]) * wv[j * 3 + 1]
                + bf2f((ushort_t)nxt[j]) * wv[j * 3 + 2];
      o[j] = (short)f2bf(tanhf(acc) * dv[j]);
    }
    *(s16x8*)&mix[(size_t)row * 1088 + d0] = o;
  } else {
    int unit = (blockIdx.x - 16384) * 4 + (threadIdx.x >> 6);  // 0..511
    int b = unit >> 6, ci = unit & 63, s = threadIdx.x & 63;
    size_t base = (((size_t)b * TT) + ci * 64) * 64 + s;
    float st = I[(b * 64 + ci) * 64 + s];
    size_t mrow = (size_t)b * TT + ci * 64;
    #pragma unroll 4
    for (int t = 0; t < 64; ++t) {
      size_t o = base + (size_t)t * 64;
      st = st * dec[o] + bb[o];
      mix[(mrow + t) * 1088 + 1024 + s] = (ushort_t)f2bf(cc[o] * st);
    }
  }
}

// ---------------- chunked scan ----------------
__global__ void scanA_kernel(const float* __restrict__ dec, const float* __restrict__ bb,
                             float* __restrict__ P, float* __restrict__ Q)
{
  int b = blockIdx.x >> 6, ci = blockIdx.x & 63, s = threadIdx.x;
  size_t base = (((size_t)b * TT) + ci * 64) * 64 + s;
  float p = 1.f, q = 0.f;
  #pragma unroll 4
  for (int t = 0; t < 64; ++t) {
    float d = dec[base + (size_t)t * 64];
    float w = bb[base + (size_t)t * 64];
    q = q * d + w; p *= d;
  }
  int o = (b * 64 + ci) * 64 + s;
  P[o] = p; Q[o] = q;
}

__global__ void scanB_kernel(const float* __restrict__ P, const float* __restrict__ Q,
                             float* __restrict__ I)
{
  int b = blockIdx.x, s = threadIdx.x;
  float pv[64], qv[64];
  #pragma unroll
  for (int ci = 0; ci < 64; ++ci) {
    int o = (b * 64 + ci) * 64 + s;
    pv[ci] = P[o]; qv[ci] = Q[o];
  }
  float st = 0.f;
  #pragma unroll
  for (int ci = 0; ci < 64; ++ci) {
    int o = (b * 64 + ci) * 64 + s;
    I[o] = st;
    st = st * pv[ci] + qv[ci];
  }
}

// ---------------- launch ----------------
extern "C" void kernel_launch(void* const* d_in, const int* in_sizes, int n_in,
                              void* d_out, int out_size, void* d_ws, size_t ws_size,
                              hipStream_t stream)
{
  (void)in_sizes; (void)n_in; (void)out_size; (void)ws_size;
  const float* x      = (const float*)d_in[0];
  const float* norm_w = (const float*)d_in[1];
  const float* norm_b = (const float*)d_in[2];
  const float* in_w   = (const float*)d_in[3];
  const float* in_b   = (const float*)d_in[4];
  const float* conv_w = (const float*)d_in[5];
  const float* conv_b = (const float*)d_in[6];
  const float* dt_w   = (const float*)d_in[7];
  const float* dt_b   = (const float*)d_in[8];
  const float* b_w    = (const float*)d_in[9];
  const float* b_b    = (const float*)d_in[10];
  const float* c_w    = (const float*)d_in[11];
  const float* c_b    = (const float*)d_in[12];
  const float* a_log  = (const float*)d_in[13];
  const float* dvec   = (const float*)d_in[14];
  const float* out_w  = (const float*)d_in[15];
  const float* out_b  = (const float*)d_in[16];
  float* out = (float*)d_out;

  char* p = (char*)d_ws;
  ushort_t* mix    = (ushort_t*)p;               // NN x 1088 bf16 (xn aliases head)
  ushort_t* xn     = mix;
  p += 71303168;
  ushort_t* xproj  = (ushort_t*)p; p += 67108864;
  char*     zreg   = p;            p += 67108864; // gates + fold scratch
  ushort_t* w1_bf  = (ushort_t*)p; p += 4194304;  // 1024x1024 bf16 (xproj weight)
  ushort_t* w3     = (ushort_t*)p; p += 524288;   // 256x1024 bf16 (orig gate W, padded)
  ushort_t* outw_bf= (ushort_t*)p; p += 2228224;
  float* P = (float*)p; p += 131072;
  float* Q = (float*)p; p += 131072;
  float* I = (float*)p; p += 131072;

  float* gdec = (float*)zreg;                        // NN x 64 f32
  float* gbb  = (float*)(zreg + 8388608);
  float* gcc  = (float*)(zreg + 16777216);
  ushort_t* inw2t  = (ushort_t*)(zreg + 33554432);   // 1024x1024 bf16 (dead after fold)
  float*    gb     = (float*)(zreg + 37748736);      // 192 f32 composite bias
  ushort_t* wgates = (ushort_t*)(zreg + 41943040);   // 256x1024 bf16 composite gate W

  // --- weight prep (merged: 2 launches) ---
  prep1_kernel<<<2624, 256, 0, stream>>>(in_w, out_w, dt_w, b_w, c_w,
                                         w1_bf, outw_bf, w3, inw2t);
  prep2_kernel<<<64, 256, 0, stream>>>(w3, inw2t, wgates,
                                       dt_w, b_w, c_w, dt_b, b_b, c_b, in_b, gb);

  ln_kernel<<<8192, 256, 0, stream>>>(x, norm_w, norm_b, xn);

  // GEMM1a: xproj = xn @ W1^T + in_b[:1024]   (M=32768, N=1024, K=1024)
  gemm256<0><<<(NN / 256) * (1024 / 256), 512, 0, stream>>>(
      xn, w1_bf, NN, 1024, 1024, in_b, xproj, nullptr);

  // GEMM2': gates = xn @ Wg^T + gb  (before conv overwrites mix/xn)
  gemm128g<<<(NN / 128) * (256 / 128), 256, 0, stream>>>(
      xn, wgates, NN, 256, 1024, gb, a_log, gdec, gbb, gcc);

  scanA_kernel<<<512, 64, 0, stream>>>(gdec, gbb, P, Q);
  scanB_kernel<<<8, 64, 0, stream>>>(P, Q, I);

  // conv (writes mix[:,:1024]) + scanC (writes mix[:,1024:]) in one launch
  convscanC_kernel<<<16512, 256, 0, stream>>>(xproj, conv_w, conv_b, dvec,
                                              gdec, gbb, gcc, I, mix);

  // GEMM3 v2: out = mix @ out_w^T + out_b + x  (K=1088, nk=17; 128x256 tile)
  gemm3_v2<<<(NN / 128) * (1024 / 256), 512, 0, stream>>>(
      mix, outw_bf, NN, 1024, 1088, out_b, x, out);
}

// Round 16
// 369.706 us; speedup vs baseline: 1.0952x; 1.0452x over previous
//
#include <hip/hip_runtime.h>

#define TT 4096
#define DD 1024
#define NN 32768   // B*T rows

typedef short s16x8 __attribute__((ext_vector_type(8)));
typedef float f32x4 __attribute__((ext_vector_type(4)));
typedef unsigned short ushort_t;

__device__ __forceinline__ unsigned short f2bf(float f) {
  unsigned u = __float_as_uint(f);
  u += 0x7FFFu + ((u >> 16) & 1u);
  return (unsigned short)(u >> 16);
}
__device__ __forceinline__ float bf2f(unsigned short h) {
  return __uint_as_float(((unsigned)h) << 16);
}
__device__ __forceinline__ void load_lds16(const void* g, void* l) {
  __builtin_amdgcn_global_load_lds(
      (const __attribute__((address_space(1))) unsigned int*)g,
      (__attribute__((address_space(3))) unsigned int*)l, 16, 0, 0);
}

// ---------------- prep1: all weight conversions in one launch ----------------
__global__ __launch_bounds__(256)
void prep1_kernel(const float* __restrict__ in_w, const float* __restrict__ out_w,
                  const float* __restrict__ dt_w, const float* __restrict__ b_w,
                  const float* __restrict__ c_w,
                  ushort_t* __restrict__ w1_bf, ushort_t* __restrict__ outw_bf,
                  ushort_t* __restrict__ w3, ushort_t* __restrict__ inw2t)
{
  __shared__ float tile[64][65];
  int blk = blockIdx.x, tid = threadIdx.x;
  if (blk < 1024) {
    int i = (blk * 256 + tid) * 4;
    float4 v = *(const float4*)&in_w[i];
    ushort4 o; o.x = f2bf(v.x); o.y = f2bf(v.y); o.z = f2bf(v.z); o.w = f2bf(v.w);
    *(ushort4*)&w1_bf[i] = o;
  } else if (blk < 2112) {
    int i = ((blk - 1024) * 256 + tid) * 4;
    if (i < 1114112) {
      float4 v = *(const float4*)&out_w[i];
      ushort4 o; o.x = f2bf(v.x); o.y = f2bf(v.y); o.z = f2bf(v.z); o.w = f2bf(v.w);
      *(ushort4*)&outw_bf[i] = o;
    }
  } else if (blk < 2368) {
    int e = ((blk - 2112) * 256 + tid) * 4;
    int row = e >> 10, col = e & 1023;
    float4 v; v.x = 0.f; v.y = 0.f; v.z = 0.f; v.w = 0.f;
    if (row < 64)       v = *(const float4*)&dt_w[(row << 10) + col];
    else if (row < 128) v = *(const float4*)&b_w[((row - 64) << 10) + col];
    else if (row < 192) v = *(const float4*)&c_w[((row - 128) << 10) + col];
    ushort4 o; o.x = f2bf(v.x); o.y = f2bf(v.y); o.z = f2bf(v.z); o.w = f2bf(v.w);
    *(ushort4*)&w3[e] = o;
  } else {
    int b2 = blk - 2368;
    int bx = b2 & 15, by = b2 >> 4;
    int tx = tid & 63, ty0 = tid >> 6;
    const float* src = in_w + 1048576;
    #pragma unroll
    for (int i = 0; i < 16; ++i) {
      int ty = ty0 * 16 + i;
      tile[ty][tx] = src[(size_t)(by * 64 + ty) * 1024 + bx * 64 + tx];
    }
    __syncthreads();
    #pragma unroll
    for (int i = 0; i < 16; ++i) {
      int ty = ty0 * 16 + i;
      inw2t[(size_t)(bx * 64 + ty) * 1024 + by * 64 + tx] = f2bf(tile[tx][ty]);
    }
  }
}

// ---------------- prep2: Wg = w3 @ inw2t (blocks 0..15) + gbias (blocks 16..63) --
__global__ __launch_bounds__(256)
void prep2_kernel(const ushort_t* __restrict__ w3, const ushort_t* __restrict__ inw2t,
                  ushort_t* __restrict__ wgates,
                  const float* __restrict__ dt_w, const float* __restrict__ b_w,
                  const float* __restrict__ c_w, const float* __restrict__ dt_b,
                  const float* __restrict__ b_b, const float* __restrict__ c_b,
                  const float* __restrict__ in_b, float* __restrict__ gb)
{
  __shared__ ushort_t As[128 * 64];
  __shared__ ushort_t Bs[128 * 64];
  const int tid = threadIdx.x;
  if (blockIdx.x >= 16) {
    int i = (blockIdx.x - 16) * 4 + (tid >> 6);
    int lane = tid & 63;
    const float* wr = i < 64 ? dt_w + (size_t)i * 1024
                    : i < 128 ? b_w + (size_t)(i - 64) * 1024
                              : c_w + (size_t)(i - 128) * 1024;
    float s = 0.f;
    for (int j = lane; j < 1024; j += 64) s += wr[j] * in_b[1024 + j];
    #pragma unroll
    for (int off = 32; off; off >>= 1) s += __shfl_xor(s, off, 64);
    if (lane == 0) {
      float bb = i < 64 ? dt_b[i] : i < 128 ? b_b[i - 64] : c_b[i - 128];
      gb[i] = s + bb;
    }
    return;
  }
  const int K = 1024, N = 1024;
  const int bid = blockIdx.x;
  const int lane = tid & 63;
  const int wid = tid >> 6;
  const int brow = (bid / 8) << 7;
  const int bcol = (bid % 8) << 7;
  const int wr = (wid >> 1) << 6;
  const int wc = (wid & 1) << 6;
  const int lane15 = lane & 15;
  const int lgrp = lane >> 4;

  f32x4 acc[4][4];
  #pragma unroll
  for (int m = 0; m < 4; ++m)
    #pragma unroll
    for (int n = 0; n < 4; ++n)
      acc[m][n] = (f32x4){0.f, 0.f, 0.f, 0.f};

  const int r0 = tid >> 3;
  const int c0 = (tid & 7) << 3;
  const ushort_t* gA = w3 + (size_t)(brow + r0) * K + c0;
  const ushort_t* gW = inw2t + (size_t)(bcol + r0) * K + c0;
  ushort_t* lA = &As[r0 * 64 + c0];
  ushort_t* lB = &Bs[r0 * 64 + c0];

  for (int k0 = 0; k0 < K; k0 += 64) {
    #pragma unroll
    for (int j = 0; j < 4; ++j) {
      load_lds16(gA + (size_t)(j * 32) * K + k0, lA + j * 32 * 64);
      load_lds16(gW + (size_t)(j * 32) * K + k0, lB + j * 32 * 64);
    }
    __syncthreads();
    #pragma unroll
    for (int kk = 0; kk < 2; ++kk) {
      s16x8 af[4], bfr[4];
      #pragma unroll
      for (int m = 0; m < 4; ++m)
        af[m] = *(const s16x8*)&As[(wr + m * 16 + lane15) * 64 + kk * 32 + lgrp * 8];
      #pragma unroll
      for (int n = 0; n < 4; ++n)
        bfr[n] = *(const s16x8*)&Bs[(wc + n * 16 + lane15) * 64 + kk * 32 + lgrp * 8];
      #pragma unroll
      for (int m = 0; m < 4; ++m)
        #pragma unroll
        for (int n = 0; n < 4; ++n)
          acc[m][n] = __builtin_amdgcn_mfma_f32_16x16x32_bf16(af[m], bfr[n], acc[m][n], 0, 0, 0);
    }
    __syncthreads();
  }

  #pragma unroll
  for (int m = 0; m < 4; ++m) {
    #pragma unroll
    for (int i = 0; i < 4; ++i) {
      const int r = brow + wr + m * 16 + lgrp * 4 + i;
      #pragma unroll
      for (int n = 0; n < 4; ++n) {
        const int col = bcol + wc + n * 16 + lane15;
        wgates[(size_t)r * N + col] = f2bf(acc[m][n][i]);
      }
    }
  }
}

// ---------------- LayerNorm -> bf16 ----------------
__global__ __launch_bounds__(256)
void ln_kernel(const float* __restrict__ x, const float* __restrict__ w,
               const float* __restrict__ bv, ushort_t* __restrict__ xn)
{
  int row = blockIdx.x * 4 + (threadIdx.x >> 6);
  int lane = threadIdx.x & 63;
  const float* xr = x + (size_t)row * DD;
  float4 v[4];
  float s = 0.f, ss = 0.f;
  #pragma unroll
  for (int j = 0; j < 4; ++j) {
    v[j] = *(const float4*)&xr[j * 256 + lane * 4];
    s  += v[j].x + v[j].y + v[j].z + v[j].w;
    ss += v[j].x * v[j].x + v[j].y * v[j].y + v[j].z * v[j].z + v[j].w * v[j].w;
  }
  #pragma unroll
  for (int off = 32; off > 0; off >>= 1) {
    s  += __shfl_xor(s, off, 64);
    ss += __shfl_xor(ss, off, 64);
  }
  float mean = s * (1.f / 1024.f);
  float var  = ss * (1.f / 1024.f) - mean * mean;
  float rinv = rsqrtf(var + 1e-5f);
  #pragma unroll
  for (int j = 0; j < 4; ++j) {
    int c = j * 256 + lane * 4;
    float4 wv = *(const float4*)&w[c];
    float4 bb = *(const float4*)&bv[c];
    ushort4 o;
    o.x = f2bf((v[j].x - mean) * rinv * wv.x + bb.x);
    o.y = f2bf((v[j].y - mean) * rinv * wv.y + bb.y);
    o.z = f2bf((v[j].z - mean) * rinv * wv.z + bb.z);
    o.w = f2bf((v[j].w - mean) * rinv * wv.w + bb.w);
    *(ushort4*)&xn[(size_t)row * DD + c] = o;
  }
}

// ---------------- 256x256 8-phase GEMM (round-4 verified schedule) ----------------
template<int EP>
__global__ __launch_bounds__(512, 2)
void gemm256(const ushort_t* __restrict__ A, const ushort_t* __restrict__ W,
             int M, int N, int K,
             const float* __restrict__ bias0,
             ushort_t* __restrict__ o0, ushort_t* __restrict__ o1)
{
  __shared__ ushort_t lds[65536];   // 128 KiB
  const int tid = threadIdx.x;
  const int lane = tid & 63;
  const int wid = tid >> 6;
  const int wr = wid >> 2;          // 0..1
  const int wc = wid & 3;           // 0..3
  const int lane15 = lane & 15;
  const int lgrp = lane >> 4;
  const int rsw = (lane15 & 7) << 4;
  const int ntn = N >> 8;
  int bid = blockIdx.x;
  { const int cpx = (int)gridDim.x >> 3; bid = (bid & 7) * cpx + (bid >> 3); }
  const int brow = (bid / ntn) << 8;
  const int bcol = (bid % ntn) << 8;
  const int nk = K >> 6;
  const int sRow = tid >> 3;        // 0..63
  const int sCol = (tid & 7) << 4;  // bytes 0..112
  const char* ldsb = (const char*)lds;
  (void)M;

#define STG(bufb, isB, h, kt) do { \
    const int ktc_ = (kt) < nk ? (kt) : nk - 1; \
    const ushort_t* gsrc_ = (isB) ? W : A; \
    const int rowb_ = ((isB) ? bcol : brow) + (h) * 128; \
    _Pragma("unroll") \
    for (int j_ = 0; j_ < 2; ++j_) { \
      const int r_ = j_ * 64 + sRow; \
      load_lds16((const char*)(gsrc_ + (size_t)(rowb_ + r_) * K) + ktc_ * 128 + (sCol ^ ((r_ & 7) << 4)), \
                 (char*)lds + (bufb) * 65536 + (isB) * 32768 + (h) * 16384 + r_ * 128 + sCol); \
    } } while (0)

#define LDA_(bufb, m, kk) \
  (*(const s16x8*)(ldsb + (bufb) * 65536 + wr * 16384 + ((m) * 16 + lane15) * 128 + (((kk) * 64 + lgrp * 16) ^ rsw)))
#define LDB_(bufb, n, kk) \
  (*(const s16x8*)(ldsb + (bufb) * 65536 + 32768 + (wc >> 1) * 16384 + ((wc & 1) * 64 + (n) * 16 + lane15) * 128 + (((kk) * 64 + lgrp * 16) ^ rsw)))

#define BARR() asm volatile("s_barrier" ::: "memory")
#define VMW2() asm volatile("s_waitcnt vmcnt(2)" ::: "memory")
#define VMW4() asm volatile("s_waitcnt vmcnt(4)" ::: "memory")

#define RDA(dst, bufb, mh) do { \
    _Pragma("unroll") for (int kk = 0; kk < 2; ++kk) \
    _Pragma("unroll") for (int q = 0; q < 4; ++q) \
      dst[kk][q] = LDA_(bufb, (mh) * 4 + q, kk); } while (0)
#define RDB(dst, bufb, nh) do { \
    _Pragma("unroll") for (int kk = 0; kk < 2; ++kk) \
    _Pragma("unroll") for (int p = 0; p < 2; ++p) \
      dst[kk][p] = LDB_(bufb, (nh) * 2 + p, kk); } while (0)

#define MFMAQ(AF, BF, mh, nh) do { \
    __builtin_amdgcn_s_setprio(1); \
    _Pragma("unroll") for (int kk = 0; kk < 2; ++kk) \
    _Pragma("unroll") for (int q = 0; q < 4; ++q) \
    _Pragma("unroll") for (int p = 0; p < 2; ++p) \
      acc[(mh) * 4 + q][(nh) * 2 + p] = __builtin_amdgcn_mfma_f32_16x16x32_bf16( \
          AF[kk][q], BF[kk][p], acc[(mh) * 4 + q][(nh) * 2 + p], 0, 0, 0); \
    __builtin_amdgcn_s_setprio(0); } while (0)

  f32x4 acc[8][4];
  #pragma unroll
  for (int m = 0; m < 8; ++m) {
    #pragma unroll
    for (int n = 0; n < 4; ++n) acc[m][n] = (f32x4){0.f, 0.f, 0.f, 0.f};
  }
  s16x8 afP[2][4], afQ[2][4];
  s16x8 b0[2][2], b1[2][2];

  STG(0, 1, 0, 0); STG(0, 0, 0, 0); STG(0, 0, 1, 0); STG(0, 1, 1, 0);
  STG(1, 1, 0, 1); STG(1, 0, 0, 1);
  VMW4(); BARR();
  RDA(afP, 0, 0); RDB(b0, 0, 0);

  const int nIter = nk >> 1;
  for (int it = 0; it < nIter; ++it) {
    const int t0 = 2 * it;
    STG(1, 0, 1, t0 + 1);
    MFMAQ(afP, b0, 0, 0);
    RDB(b1, 0, 1); BARR();
    STG(1, 1, 1, t0 + 1);
    MFMAQ(afP, b1, 0, 1);
    RDA(afQ, 0, 1); BARR();
    STG(0, 1, 0, t0 + 2);
    MFMAQ(afQ, b1, 1, 1);
    VMW2(); BARR();
    STG(0, 0, 0, t0 + 2);
    MFMAQ(afQ, b0, 1, 0);
    RDA(afP, 1, 0); RDB(b1, 1, 1); BARR();
    STG(0, 0, 1, t0 + 2);
    MFMAQ(afP, b1, 0, 1);
    RDB(b0, 1, 0); BARR();
    STG(0, 1, 1, t0 + 2);
    MFMAQ(afP, b0, 0, 0);
    RDA(afQ, 1, 1); BARR();
    STG(1, 1, 0, t0 + 3);
    MFMAQ(afQ, b0, 1, 0);
    VMW2(); BARR();
    STG(1, 0, 0, t0 + 3);
    MFMAQ(afQ, b1, 1, 1);
    RDA(afP, 0, 0); RDB(b0, 0, 0); BARR();
  }
  if (nk & 1) {
    MFMAQ(afP, b0, 0, 0);
    RDB(b1, 0, 1);
    MFMAQ(afP, b1, 0, 1);
    RDA(afQ, 0, 1);
    MFMAQ(afQ, b1, 1, 1);
    MFMAQ(afQ, b0, 1, 0);
  }

#undef STG
#undef LDA_
#undef LDB_
#undef BARR
#undef VMW2
#undef VMW4
#undef RDA
#undef RDB
#undef MFMAQ

  #pragma unroll
  for (int m = 0; m < 8; ++m) {
    #pragma unroll
    for (int i = 0; i < 4; ++i) {
      const int r = brow + wr * 128 + m * 16 + lgrp * 4 + i;
      #pragma unroll
      for (int n = 0; n < 4; ++n) {
        const int col = bcol + wc * 64 + n * 16 + lane15;
        float v = acc[m][n][i] + bias0[col];
        if (col < DD) o0[(size_t)r * DD + col] = f2bf(v);
        else          o1[(size_t)r * DD + (col - DD)] = f2bf(v);
      }
    }
  }
}

// ---------------- GEMM3 v3: 128x128 tile, BK=64, 512 thr (8 waves), 2 blk/CU ---
// 8 waves = 2(M:64) x 4(N:32); per-wave 64x32 out (acc 32 VGPR); LDS 64 KiB.
// 16 waves/CU for latency hiding. Counted vmcnt(4) (4 stage loads/thread).
// Canonical staging (lds_off(lane)=base+16*lane) + verified 0-conflict swizzle.
__global__ __launch_bounds__(512, 2)
void gemm3_v3(const ushort_t* __restrict__ A, const ushort_t* __restrict__ W,
              int M, int N, int K,
              const float* __restrict__ bias, const float* __restrict__ resid,
              float* __restrict__ outf)
{
  __shared__ ushort_t lds[32768];   // 64 KiB: per buf 32KB = A[128][64] + B[128][64]
  const int tid = threadIdx.x;
  const int lane = tid & 63;
  const int wid = tid >> 6;         // 0..7
  const int wrh = wid >> 2;         // 0..1 (64-row half)
  const int wcq = wid & 3;          // 0..3 (32-col quarter)
  const int lane15 = lane & 15;
  const int lgrp = lane >> 4;
  const int rsw = (lane15 & 7) << 4;
  const int ntn = N >> 7;           // 8
  int bid = blockIdx.x;
  { const int cpx = (int)gridDim.x >> 3; bid = (bid & 7) * cpx + (bid >> 3); }
  const int brow = (bid / ntn) << 7;
  const int bcol = (bid % ntn) << 7;
  const int nk = K >> 6;            // 17
  const int sRow = tid >> 3;        // 0..63 (512 thr)
  const int sCol = (tid & 7) << 4;  // bytes 0..112
  const char* ldsb = (const char*)lds;
  (void)M;

  f32x4 acc[4][2];
  #pragma unroll
  for (int q = 0; q < 4; ++q)
    #pragma unroll
    for (int p = 0; p < 2; ++p) acc[q][p] = (f32x4){0.f, 0.f, 0.f, 0.f};

#define STG3(bufb, kt) do { \
    _Pragma("unroll") \
    for (int j_ = 0; j_ < 2; ++j_) { \
      const int r_ = j_ * 64 + sRow; \
      load_lds16((const char*)(A + (size_t)(brow + r_) * K) + (kt) * 128 + (sCol ^ ((r_ & 7) << 4)), \
                 (char*)lds + (bufb) * 32768 + r_ * 128 + sCol); \
      load_lds16((const char*)(W + (size_t)(bcol + r_) * K) + (kt) * 128 + (sCol ^ ((r_ & 7) << 4)), \
                 (char*)lds + (bufb) * 32768 + 16384 + r_ * 128 + sCol); \
    } } while (0)
#define BARR3() asm volatile("s_barrier" ::: "memory")
#define VMW4_() asm volatile("s_waitcnt vmcnt(4)" ::: "memory")
#define VMW0_() asm volatile("s_waitcnt vmcnt(0)" ::: "memory")

  STG3(0, 0);     // 4 loads/thread in flight

  for (int t = 0; t < nk; ++t) {
    const int cur = t & 1;
    if (t + 1 < nk) { STG3(cur ^ 1, t + 1); VMW4_(); }
    else            { VMW0_(); }
    BARR3();
    #pragma unroll
    for (int kk = 0; kk < 2; ++kk) {
      s16x8 af[4], bf[2];
      #pragma unroll
      for (int q = 0; q < 4; ++q)
        af[q] = *(const s16x8*)(ldsb + cur * 32768 +
                 (wrh * 64 + q * 16 + lane15) * 128 + ((kk * 64 + lgrp * 16) ^ rsw));
      #pragma unroll
      for (int p = 0; p < 2; ++p)
        bf[p] = *(const s16x8*)(ldsb + cur * 32768 + 16384 +
                 (wcq * 32 + p * 16 + lane15) * 128 + ((kk * 64 + lgrp * 16) ^ rsw));
      __builtin_amdgcn_s_setprio(1);
      #pragma unroll
      for (int q = 0; q < 4; ++q)
        #pragma unroll
        for (int p = 0; p < 2; ++p)
          acc[q][p] = __builtin_amdgcn_mfma_f32_16x16x32_bf16(af[q], bf[p], acc[q][p], 0, 0, 0);
      __builtin_amdgcn_s_setprio(0);
    }
    BARR3();
  }
#undef STG3
#undef BARR3
#undef VMW4_
#undef VMW0_

  #pragma unroll
  for (int q = 0; q < 4; ++q) {
    #pragma unroll
    for (int i = 0; i < 4; ++i) {
      const int r = brow + wrh * 64 + q * 16 + lgrp * 4 + i;
      #pragma unroll
      for (int p = 0; p < 2; ++p) {
        const int col = bcol + wcq * 32 + p * 16 + lane15;
        outf[(size_t)r * DD + col] = acc[q][p][i] + bias[col] + resid[(size_t)r * DD + col];
      }
    }
  }
}

// ---------------- 128x128 2-phase GEMM: gates from xn (composite W/bias) --------
__global__ __launch_bounds__(256)
void gemm128g(const ushort_t* __restrict__ A, const ushort_t* __restrict__ W,
              int M, int N, int K,
              const float* __restrict__ gb, const float* __restrict__ alog,
              float* __restrict__ g0, float* __restrict__ g1, float* __restrict__ g2)
{
  __shared__ ushort_t As[128 * 64];
  __shared__ ushort_t Bs[128 * 64];
  const int tid = threadIdx.x;
  const int lane = tid & 63;
  const int wid = tid >> 6;
  const int ntn = N >> 7;
  const int brow = (blockIdx.x / ntn) << 7;
  const int bcol = (blockIdx.x % ntn) << 7;
  const int wr = (wid >> 1) << 6;
  const int wc = (wid & 1) << 6;
  const int lane15 = lane & 15;
  const int lgrp = lane >> 4;
  (void)M;

  f32x4 acc[4][4];
  #pragma unroll
  for (int m = 0; m < 4; ++m)
    #pragma unroll
    for (int n = 0; n < 4; ++n)
      acc[m][n] = (f32x4){0.f, 0.f, 0.f, 0.f};

  const int r0 = tid >> 3;
  const int c0 = (tid & 7) << 3;
  const ushort_t* gA = A + (size_t)(brow + r0) * K + c0;
  const ushort_t* gW = W + (size_t)(bcol + r0) * K + c0;
  ushort_t* lA = &As[r0 * 64 + c0];
  ushort_t* lB = &Bs[r0 * 64 + c0];

  for (int k0 = 0; k0 < K; k0 += 64) {
    #pragma unroll
    for (int j = 0; j < 4; ++j) {
      load_lds16(gA + (size_t)(j * 32) * K + k0, lA + j * 32 * 64);
      load_lds16(gW + (size_t)(j * 32) * K + k0, lB + j * 32 * 64);
    }
    __syncthreads();
    #pragma unroll
    for (int kk = 0; kk < 2; ++kk) {
      s16x8 af[4], bfr[4];
      #pragma unroll
      for (int m = 0; m < 4; ++m)
        af[m] = *(const s16x8*)&As[(wr + m * 16 + lane15) * 64 + kk * 32 + lgrp * 8];
      #pragma unroll
      for (int n = 0; n < 4; ++n)
        bfr[n] = *(const s16x8*)&Bs[(wc + n * 16 + lane15) * 64 + kk * 32 + lgrp * 8];
      #pragma unroll
      for (int m = 0; m < 4; ++m)
        #pragma unroll
        for (int n = 0; n < 4; ++n)
          acc[m][n] = __builtin_amdgcn_mfma_f32_16x16x32_bf16(af[m], bfr[n], acc[m][n], 0, 0, 0);
    }
    __syncthreads();
  }

  #pragma unroll
  for (int m = 0; m < 4; ++m) {
    #pragma unroll
    for (int i = 0; i < 4; ++i) {
      const int r = brow + wr + m * 16 + lgrp * 4 + i;
      #pragma unroll
      for (int n = 0; n < 4; ++n) {
        const int col = bcol + wc + n * 16 + lane15;
        float v = acc[m][n][i];
        if (col < 64) {
          float u = v + gb[col];
          float sp = (u > 20.f) ? u : log1pf(expf(u));
          g0[(size_t)r * 64 + col] = expf(-expf(alog[col]) * (sp + 1e-4f));
        } else if (col < 128) {
          g1[(size_t)r * 64 + (col - 64)] = tanhf(v + gb[col]);
        } else if (col < 192) {
          g2[(size_t)r * 64 + (col - 128)] = tanhf(v + gb[col]);
        }
      }
    }
  }
}

// ---------------- conv (blocks 0..16383) + scanC (blocks 16384..16511) ----------
__global__ __launch_bounds__(256)
void convscanC_kernel(const ushort_t* __restrict__ xp, const float* __restrict__ cw,
                      const float* __restrict__ cb, const float* __restrict__ dvec,
                      const float* __restrict__ dec, const float* __restrict__ bb,
                      const float* __restrict__ cc, const float* __restrict__ I,
                      ushort_t* __restrict__ mix)
{
  if (blockIdx.x < 16384) {
    int idx = blockIdx.x * 256 + threadIdx.x;
    int row = idx >> 7;
    int d0 = (idx & 127) << 3;
    int t = row & (TT - 1);
    s16x8 cur = *(const s16x8*)&xp[(size_t)row * DD + d0];
    s16x8 prv; s16x8 nxt;
    #pragma unroll
    for (int j = 0; j < 8; ++j) { prv[j] = 0; nxt[j] = 0; }
    if (t > 0)      prv = *(const s16x8*)&xp[(size_t)(row - 1) * DD + d0];
    if (t < TT - 1) nxt = *(const s16x8*)&xp[(size_t)(row + 1) * DD + d0];
    float wv[24];
    #pragma unroll
    for (int j = 0; j < 6; ++j) *(float4*)&wv[j * 4] = *(const float4*)&cw[d0 * 3 + j * 4];
    float cbv[8], dv[8];
    *(float4*)&cbv[0] = *(const float4*)&cb[d0];
    *(float4*)&cbv[4] = *(const float4*)&cb[d0 + 4];
    *(float4*)&dv[0]  = *(const float4*)&dvec[d0];
    *(float4*)&dv[4]  = *(const float4*)&dvec[d0 + 4];
    s16x8 o;
    #pragma unroll
    for (int j = 0; j < 8; ++j) {
      float acc = cbv[j] + bf2f((ushort_t)prv[j]) * wv[j * 3]
                + bf2f((ushort_t)cur[j]) * wv[j * 3 + 1]
                + bf2f((ushort_t)nxt[j]) * wv[j * 3 + 2];
      o[j] = (short)f2bf(tanhf(acc) * dv[j]);
    }
    *(s16x8*)&mix[(size_t)row * 1088 + d0] = o;
  } else {
    int unit = (blockIdx.x - 16384) * 4 + (threadIdx.x >> 6);  // 0..511
    int b = unit >> 6, ci = unit & 63, s = threadIdx.x & 63;
    size_t base = (((size_t)b * TT) + ci * 64) * 64 + s;
    float st = I[(b * 64 + ci) * 64 + s];
    size_t mrow = (size_t)b * TT + ci * 64;
    #pragma unroll 4
    for (int t = 0; t < 64; ++t) {
      size_t o = base + (size_t)t * 64;
      st = st * dec[o] + bb[o];
      mix[(mrow + t) * 1088 + 1024 + s] = (ushort_t)f2bf(cc[o] * st);
    }
  }
}

// ---------------- chunked scan ----------------
__global__ void scanA_kernel(const float* __restrict__ dec, const float* __restrict__ bb,
                             float* __restrict__ P, float* __restrict__ Q)
{
  int b = blockIdx.x >> 6, ci = blockIdx.x & 63, s = threadIdx.x;
  size_t base = (((size_t)b * TT) + ci * 64) * 64 + s;
  float p = 1.f, q = 0.f;
  #pragma unroll 4
  for (int t = 0; t < 64; ++t) {
    float d = dec[base + (size_t)t * 64];
    float w = bb[base + (size_t)t * 64];
    q = q * d + w; p *= d;
  }
  int o = (b * 64 + ci) * 64 + s;
  P[o] = p; Q[o] = q;
}

__global__ void scanB_kernel(const float* __restrict__ P, const float* __restrict__ Q,
                             float* __restrict__ I)
{
  int b = blockIdx.x, s = threadIdx.x;
  float pv[64], qv[64];
  #pragma unroll
  for (int ci = 0; ci < 64; ++ci) {
    int o = (b * 64 + ci) * 64 + s;
    pv[ci] = P[o]; qv[ci] = Q[o];
  }
  float st = 0.f;
  #pragma unroll
  for (int ci = 0; ci < 64; ++ci) {
    int o = (b * 64 + ci) * 64 + s;
    I[o] = st;
    st = st * pv[ci] + qv[ci];
  }
}

// ---------------- launch ----------------
extern "C" void kernel_launch(void* const* d_in, const int* in_sizes, int n_in,
                              void* d_out, int out_size, void* d_ws, size_t ws_size,
                              hipStream_t stream)
{
  (void)in_sizes; (void)n_in; (void)out_size; (void)ws_size;
  const float* x      = (const float*)d_in[0];
  const float* norm_w = (const float*)d_in[1];
  const float* norm_b = (const float*)d_in[2];
  const float* in_w   = (const float*)d_in[3];
  const float* in_b   = (const float*)d_in[4];
  const float* conv_w = (const float*)d_in[5];
  const float* conv_b = (const float*)d_in[6];
  const float* dt_w   = (const float*)d_in[7];
  const float* dt_b   = (const float*)d_in[8];
  const float* b_w    = (const float*)d_in[9];
  const float* b_b    = (const float*)d_in[10];
  const float* c_w    = (const float*)d_in[11];
  const float* c_b    = (const float*)d_in[12];
  const float* a_log  = (const float*)d_in[13];
  const float* dvec   = (const float*)d_in[14];
  const float* out_w  = (const float*)d_in[15];
  const float* out_b  = (const float*)d_in[16];
  float* out = (float*)d_out;

  char* p = (char*)d_ws;
  ushort_t* mix    = (ushort_t*)p;               // NN x 1088 bf16 (xn aliases head)
  ushort_t* xn     = mix;
  p += 71303168;
  ushort_t* xproj  = (ushort_t*)p; p += 67108864;
  char*     zreg   = p;            p += 67108864; // gates + fold scratch
  ushort_t* w1_bf  = (ushort_t*)p; p += 4194304;  // 1024x1024 bf16 (xproj weight)
  ushort_t* w3     = (ushort_t*)p; p += 524288;   // 256x1024 bf16 (orig gate W, padded)
  ushort_t* outw_bf= (ushort_t*)p; p += 2228224;
  float* P = (float*)p; p += 131072;
  float* Q = (float*)p; p += 131072;
  float* I = (float*)p; p += 131072;

  float* gdec = (float*)zreg;                        // NN x 64 f32
  float* gbb  = (float*)(zreg + 8388608);
  float* gcc  = (float*)(zreg + 16777216);
  ushort_t* inw2t  = (ushort_t*)(zreg + 33554432);   // 1024x1024 bf16 (dead after fold)
  float*    gb     = (float*)(zreg + 37748736);      // 192 f32 composite bias
  ushort_t* wgates = (ushort_t*)(zreg + 41943040);   // 256x1024 bf16 composite gate W

  // --- weight prep (merged: 2 launches) ---
  prep1_kernel<<<2624, 256, 0, stream>>>(in_w, out_w, dt_w, b_w, c_w,
                                         w1_bf, outw_bf, w3, inw2t);
  prep2_kernel<<<64, 256, 0, stream>>>(w3, inw2t, wgates,
                                       dt_w, b_w, c_w, dt_b, b_b, c_b, in_b, gb);

  ln_kernel<<<8192, 256, 0, stream>>>(x, norm_w, norm_b, xn);

  // GEMM1a: xproj = xn @ W1^T + in_b[:1024]   (M=32768, N=1024, K=1024)
  gemm256<0><<<(NN / 256) * (1024 / 256), 512, 0, stream>>>(
      xn, w1_bf, NN, 1024, 1024, in_b, xproj, nullptr);

  // GEMM2': gates = xn @ Wg^T + gb  (before conv overwrites mix/xn)
  gemm128g<<<(NN / 128) * (256 / 128), 256, 0, stream>>>(
      xn, wgates, NN, 256, 1024, gb, a_log, gdec, gbb, gcc);

  scanA_kernel<<<512, 64, 0, stream>>>(gdec, gbb, P, Q);
  scanB_kernel<<<8, 64, 0, stream>>>(P, Q, I);

  // conv (writes mix[:,:1024]) + scanC (writes mix[:,1024:]) in one launch
  convscanC_kernel<<<16512, 256, 0, stream>>>(xproj, conv_w, conv_b, dvec,
                                              gdec, gbb, gcc, I, mix);

  // GEMM3 v3: out = mix @ out_w^T + out_b + x  (K=1088, nk=17; 8 waves, 2 blk/CU)
  gemm3_v3<<<(NN / 128) * (1024 / 128), 512, 0, stream>>>(
      mix, outw_bf, NN, 1024, 1088, out_b, x, out);
}